// Round 7
// baseline (424.043 us; speedup 1.0000x reference)
//
#include <hip/hip_runtime.h>
#include <cstdint>
#include <math.h>

#define K_TOK 2048
#define NPAIR 16      // token pairs per lane (K_TOK / 2 / 64)
#define BLK   512
#define WPB   8       // waves per block
#define RPW   2       // rows per wave -> 16 rows per block

typedef float v2f __attribute__((ext_vector_type(2)));

// monotonic float->uint key (total order == float order, handles negatives)
__device__ __forceinline__ uint32_t f2key(float f) {
    uint32_t u = __float_as_uint(f);
    return u ^ ((uint32_t)(((int32_t)u) >> 31) | 0x80000000u);
}

// ---------------- DPP wave64 primitives (ctrl args constexpr) ----------------
template<int CTRL, int RM, int BM, bool BC>
__device__ __forceinline__ int dpp_i(int old, int v) {
    return __builtin_amdgcn_update_dpp(old, v, CTRL, RM, BM, BC);
}
__device__ __forceinline__ int wave_scan_incl(int v) {
    v += dpp_i<0x111, 0xf, 0xf, true >(0, v);
    v += dpp_i<0x112, 0xf, 0xf, true >(0, v);
    v += dpp_i<0x114, 0xf, 0xf, true >(0, v);
    v += dpp_i<0x118, 0xf, 0xf, true >(0, v);
    v += dpp_i<0x142, 0xa, 0xf, false>(0, v);
    v += dpp_i<0x143, 0xc, 0xf, false>(0, v);
    return v;
}
template<int M>
__device__ __forceinline__ uint32_t lxu(uint32_t x) {
    if constexpr (M == 1)       return (uint32_t)dpp_i<0xB1,  0xf, 0xf, true>(0, (int)x);
    else if constexpr (M == 2)  return (uint32_t)dpp_i<0x4E,  0xf, 0xf, true>(0, (int)x);
    else if constexpr (M == 8)  return (uint32_t)dpp_i<0x128, 0xf, 0xf, true>(0, (int)x);
    else if constexpr (M == 4)  return (uint32_t)__builtin_amdgcn_ds_swizzle((int)x, 0x101F);
    else if constexpr (M == 16) return (uint32_t)__builtin_amdgcn_ds_swizzle((int)x, 0x401F);
    else                        return (uint32_t)__shfl_xor((int)x, 32, 64);
}
template<int M>
__device__ __forceinline__ uint64_t lxu64(uint64_t x) {
    uint32_t h = lxu<M>((uint32_t)(x >> 32));
    uint32_t l = lxu<M>((uint32_t)x);
    return ((uint64_t)h << 32) | l;
}

// ---------------- prep kernels ----------------
// Split pair streams: bA[P] = {b2[2P],b2[2P+1],b3[2P],b3[2P+1]},
//                     bB[P] = {b4[2P],b4[2P+1],b5[2P],b5[2P+1]}
__global__ void prep_tok(const float* __restrict__ mpt,
                         float4* __restrict__ bA, float4* __restrict__ bB,
                         float* __restrict__ sbout) {
    #pragma clang fp contract(off)
    int P = blockIdx.x * blockDim.x + threadIdx.x;
    if (P >= K_TOK / 2) return;
    int k0 = 2 * P, k1 = 2 * P + 1;
    float u0 = mpt[k0*6+0], u1 = mpt[k0*6+1], u2 = mpt[k0*6+2];
    float u3 = mpt[k0*6+3], u4 = mpt[k0*6+4], u5 = mpt[k0*6+5];
    float w0 = mpt[k1*6+0], w1 = mpt[k1*6+1], w2 = mpt[k1*6+2];
    float w3 = mpt[k1*6+3], w4 = mpt[k1*6+4], w5 = mpt[k1*6+5];
    float s0 = ((((u0*u0+u1*u1)+u2*u2)+u3*u3)+u4*u4)+u5*u5;
    float s1 = ((((w0*w0+w1*w1)+w2*w2)+w3*w3)+w4*w4)+w5*w5;
    bA[P] = make_float4(u2, w2, u3, w3);
    bB[P] = make_float4(u4, w4, u5, w5);
    sbout[k0] = s0; sbout[k1] = s1;
}

__global__ void prep_frame(const float* __restrict__ traj_pos,
                           const float* __restrict__ traj_theta,
                           float4* __restrict__ aA, float* __restrict__ saA, int N) {
    #pragma clang fp contract(off)
    int n = blockIdx.x * blockDim.x + threadIdx.x;
    if (n >= N) return;
    const float* tp = traj_pos + (size_t)n*6;
    float p0x=tp[0], p0y=tp[1];
    float dx1=tp[2]-p0x, dy1=tp[3]-p0y;
    float dx2=tp[4]-p0x, dy2=tp[5]-p0y;
    float th = traj_theta[n];
    float c = (float)cos((double)th);
    float s = (float)sin((double)th);
    float ns = -s;
    float a2 = c*dx1 + s*dy1;
    float a3 = ns*dx1 + c*dy1;
    float a4 = c*dx2 + s*dy2;
    float a5 = ns*dx2 + c*dy2;
    float q2=a2*a2,q3=a3*a3,q4=a4*a4,q5=a5*a5;
    float sa = ((q2+q3)+q4)+q5;
    aA[n] = make_float4(a2,a3,a4,a5);
    saA[n] = sa;
}

__global__ void prep_gumbel(const float* __restrict__ gu, float* __restrict__ g, int total) {
    #pragma clang fp contract(off)
    int i = blockIdx.x * blockDim.x + threadIdx.x;
    if (i >= total) return;
    const float C1F = (float)(1.0 - 2.0*1e-7);
    float u = gu[i];
    float t = u * C1F;
    t = t + 1e-7f;
    float li = (float)log((double)t);
    float ni = -li;
    float lo = (float)log((double)ni);
    g[i] = -lo;
}

// wave-uniform count via ballot (v_cmp on VALU, bcnt/add on SALU pipe)
__device__ __forceinline__ int count_le_sc(const v2f (&dd)[NPAIR], float T) {
    int c = 0;
    #pragma unroll
    for (int p = 0; p < NPAIR; ++p) {
        c += (int)__popcll(__ballot(dd[p].x <= T));
        c += (int)__popcll(__ballot(dd[p].y <= T));
    }
    return c;
}
__device__ __forceinline__ int count_key_sc(const v2f (&dd)[NPAIR], uint32_t A) {
    int c = 0;
    #pragma unroll
    for (int p = 0; p < NPAIR; ++p) {
        c += (int)__popcll(__ballot(f2key(dd[p].x) <= A));
        c += (int)__popcll(__ballot(f2key(dd[p].y) <= A));
    }
    return c;
}

// ---------------- per-row selection (inlined; dd bound statically) ----------------
__device__ __forceinline__ void select_row(
        const v2f (&dd)[NPAIR], float a2, float a3, float a4, float a5, float sa,
        int n, int lane, uint32_t* sCrow,
        const float4* __restrict__ bA, const float4* __restrict__ bB,
        const float* __restrict__ sSB,
        const float* __restrict__ gtab, const float* __restrict__ gumbel, int useG,
        const float* __restrict__ token_src, float* __restrict__ out) {
    #pragma clang fp contract(off)
    // per-lane min
    float lmin = INFINITY;
    #pragma unroll
    for (int p = 0; p < NPAIR; ++p) {
        lmin = fminf(lmin, dd[p].x);
        lmin = fminf(lmin, dd[p].y);
    }
    // bitonic ascending sort of lane minima -> order stats
    {
        float v = lmin;
        #define FST(K2,J2) { float o = __uint_as_float(lxu<J2>(__float_as_uint(v))); \
            bool up = ((lane & K2) == 0) == ((lane & J2) == 0); \
            v = up ? fminf(v, o) : fmaxf(v, o); }
        FST(2,1)
        FST(4,2)  FST(4,1)
        FST(8,4)  FST(8,2)  FST(8,1)
        FST(16,8) FST(16,4) FST(16,2) FST(16,1)
        FST(32,16) FST(32,8) FST(32,4) FST(32,2) FST(32,1)
        FST(64,32) FST(64,16) FST(64,8) FST(64,4) FST(64,2) FST(64,1)
        #undef FST
        lmin = v;
    }
    float gmn = __uint_as_float((uint32_t)__builtin_amdgcn_readlane((int)__float_as_uint(lmin), 0));
    float T0  = __uint_as_float((uint32_t)__builtin_amdgcn_readlane((int)__float_as_uint(lmin), 31));

    // threshold with count(d <= T) in [32,64]; counts on scalar pipe
    float T = T0;
    int cnt = count_le_sc(dd, T0);
    bool done = (cnt >= 32 && cnt <= 64);
    float loV = gmn, hiV = T0;
    for (int it = 0; it < 12 && !done; ++it) {
        float mid = 0.5f * (loV + hiV);
        if (!(mid > loV && mid < hiV)) break;
        int c = count_le_sc(dd, mid);
        if (c < 32) loV = mid;
        else if (c > 64) hiV = mid;
        else { cnt = c; T = mid; done = true; }
    }
    uint32_t A = 0u;
    bool useKey = false;
    if (!done) {
        // exact bitwise binary search fallback (cold, provably correct)
        bool found = false; int ccf = 0;
        for (int b = 31; b >= 0; --b) {
            uint32_t T2 = A | ((1u << b) - 1u);
            int cc = count_key_sc(dd, T2);
            if (cc >= 32) { if (cc <= 64) { A = T2; ccf = cc; found = true; break; } }
            else A |= (1u << b);
        }
        if (!found) ccf = count_key_sc(dd, A);
        cnt = ccf;
        useKey = true;
    }
    int cnt_cap = cnt > 64 ? 64 : cnt;

    // per-lane candidate mask at the accepted threshold
    uint32_t cmask = 0;
    if (!useKey) {
        #pragma unroll
        for (int p = 0; p < NPAIR; ++p) {
            if (dd[p].x <= T) cmask |= (1u << (2*p));
            if (dd[p].y <= T) cmask |= (1u << (2*p+1));
        }
    } else {
        #pragma unroll
        for (int p = 0; p < NPAIR; ++p) {
            if (f2key(dd[p].x) <= A) cmask |= (1u << (2*p));
            if (f2key(dd[p].y) <= A) cmask |= (1u << (2*p+1));
        }
    }

    // sparse compaction: store token index only
    {
        int lc  = __popc(cmask);
        int pos = wave_scan_incl(lc) - lc;   // exclusive prefix
        uint32_t m = cmask;
        while (m) {
            int j = __builtin_ctz(m);
            m &= m - 1;
            int token = 2 * ((j >> 1) * 64 + lane) + (j & 1);
            if (pos < 64) sCrow[pos] = (uint32_t)token;
            ++pos;
        }
    }
    asm volatile("s_waitcnt lgkmcnt(0)" ::: "memory");

    // read back + exact recompute (identical op sequence -> identical bits)
    uint64_t bv;
    if (lane < cnt_cap) {
        uint32_t idxv = sCrow[lane];
        uint32_t P = idxv >> 1;
        float4 q0 = bA[P];
        float4 q1 = bB[P];
        int h = (int)(idxv & 1u);
        float bx = h ? q0.y : q0.x;
        float by = h ? q0.w : q0.z;
        float bz = h ? q1.y : q1.x;
        float bw = h ? q1.w : q1.z;
        float sbv = sSB[idxv];
        float d0 = a2 * bx;
        d0 = fmaf(a3, by, d0);
        d0 = fmaf(a4, bz, d0);
        d0 = fmaf(a5, bw, d0);
        float ss = sa + sbv;
        float dist = fmaf(-2.0f, d0, ss);
        bv = ((uint64_t)f2key(dist) << 16) | (uint64_t)idxv;
    } else {
        bv = ~0ull;
    }

    // bitonic sort of 64 candidates, ascending (key,idx); slot l -> lane l
    #define UST(K2,J2) { uint64_t o = lxu64<J2>(bv); \
        bool up = ((lane & K2) == 0) == ((lane & J2) == 0); \
        bv = ((o < bv) == up) ? o : bv; }
    UST(2,1)
    UST(4,2)  UST(4,1)
    UST(8,4)  UST(8,2)  UST(8,1)
    UST(16,8) UST(16,4) UST(16,2) UST(16,1)
    UST(32,16) UST(32,8) UST(32,4) UST(32,2) UST(32,1)
    UST(64,32) UST(64,16) UST(64,8) UST(64,4) UST(64,2) UST(64,1)
    #undef UST

    // gumbel-argmax over 32 sorted slots (tie -> lower slot)
    float dsel;
    {
        uint32_t kbits = (uint32_t)(bv >> 16);
        uint32_t mkb = ((uint32_t)((~(int32_t)kbits) >> 31)) | 0x80000000u;
        dsel = __uint_as_float(kbits ^ mkb);
    }
    int tok = (int)(bv & 0xFFFFu);
    uint32_t kh = 0u, kl = 0u;
    if (lane < 32) {
        float neg   = -dsel;
        float logit = (-1e-6f) + neg;
        float g;
        if (useG) {
            g = gtab[(size_t)n * 32 + lane];
        } else {
            const float C1F = (float)(1.0 - 2.0 * 1e-7);
            float u = gumbel[(size_t)n * 32 + lane];
            float t = u * C1F;
            t = t + 1e-7f;
            float li = (float)log((double)t);
            float ni = -li;
            float lo2 = (float)log((double)ni);
            g = -lo2;
        }
        float score = logit + g;
        kh = f2key(score);
        kl = ((uint32_t)(63 - lane) << 11) | (uint32_t)tok;  // tie -> lower slot
    }
    #define MAXST(CTRL, RM) { \
        uint32_t oh = (uint32_t)dpp_i<CTRL, RM, 0xf, false>((int)kh, (int)kh); \
        uint32_t ol = (uint32_t)dpp_i<CTRL, RM, 0xf, false>((int)kl, (int)kl); \
        if (((((uint64_t)oh << 32) | ol)) > ((((uint64_t)kh << 32) | kl))) { kh = oh; kl = ol; } }
    MAXST(0x111, 0xf) MAXST(0x112, 0xf) MAXST(0x114, 0xf) MAXST(0x118, 0xf)
    MAXST(0x142, 0xa) MAXST(0x143, 0xc)
    #undef MAXST
    uint32_t wl = (uint32_t)__builtin_amdgcn_readlane((int)kl, 63);
    int tw = (int)(wl & 0x7FFu);

    if (lane < 22) out[(size_t)n * 22 + lane] = token_src[(size_t)tw * 22 + lane];
}

// ---------------- main kernel ----------------
__global__ __launch_bounds__(BLK, 4) void topk_kernel(
        const float* __restrict__ traj_pos, const float* __restrict__ traj_theta,
        const float4* __restrict__ bA, const float4* __restrict__ bB,
        const float* __restrict__ sbg,
        const float4* __restrict__ aAg, const float* __restrict__ saAg,
        const float* __restrict__ gtab,
        const float* __restrict__ token_src, const float* __restrict__ gumbel,
        float* __restrict__ out, int Nrows, int useFrame, int useG) {
    #pragma clang fp contract(off)
    __shared__ float    sSB[K_TOK];            // 8 KB
    __shared__ uint32_t sCidx[WPB][64];        // 2 KB

    const int tid = threadIdx.x;
    {
        const float4* s4 = (const float4*)sbg;
        ((float4*)sSB)[tid] = s4[tid];         // 8 KB staged
    }
    __syncthreads();

    const int wv   = tid >> 6;
    const int lane = tid & 63;
    const int n0   = blockIdx.x * (WPB * RPW) + wv;       // row 0 of this wave
    const int n1   = n0 + WPB;                            // row 1 of this wave

    // ---- frames for both rows
    float a2_0=0, a3_0=0, a4_0=0, a5_0=0, sa_0=0;
    float a2_1=0, a3_1=0, a4_1=0, a5_1=0, sa_1=0;
    bool has0 = (n0 < Nrows), has1 = (n1 < Nrows);
    if (useFrame) {
        if (has0) { float4 av = aAg[n0]; a2_0=av.x; a3_0=av.y; a4_0=av.z; a5_0=av.w; sa_0=saAg[n0]; }
        if (has1) { float4 av = aAg[n1]; a2_1=av.x; a3_1=av.y; a4_1=av.z; a5_1=av.w; sa_1=saAg[n1]; }
    } else {
        for (int r = 0; r < 2; ++r) {
            int n = r ? n1 : n0;
            if (n >= Nrows) continue;
            const float* tp = traj_pos + (size_t)n * 6;
            float p0x = tp[0], p0y = tp[1];
            float dx1 = tp[2] - p0x, dy1 = tp[3] - p0y;
            float dx2 = tp[4] - p0x, dy2 = tp[5] - p0y;
            float th = traj_theta[n];
            float c = (float)cos((double)th);
            float s = (float)sin((double)th);
            float ns = -s;
            float a2 = c*dx1 + s*dy1;
            float a3 = ns*dx1 + c*dy1;
            float a4 = c*dx2 + s*dy2;
            float a5 = ns*dx2 + c*dy2;
            float q2 = a2*a2, q3 = a3*a3, q4 = a4*a4, q5 = a5*a5;
            float sa = ((q2 + q3) + q4) + q5;
            if (r) { a2_1=a2; a3_1=a3; a4_1=a4; a5_1=a5; sa_1=sa; }
            else   { a2_0=a2; a3_0=a3; a4_0=a4; a5_0=a5; sa_0=sa; }
        }
    }

    // ---- shared-B packed distance loop for both rows
    const v2f a2v0={a2_0,a2_0}, a3v0={a3_0,a3_0}, a4v0={a4_0,a4_0}, a5v0={a5_0,a5_0}, sav0={sa_0,sa_0};
    const v2f a2v1={a2_1,a2_1}, a3v1={a3_1,a3_1}, a4v1={a4_1,a4_1}, a5v1={a5_1,a5_1}, sav1={sa_1,sa_1};
    const v2f n2v = { -2.0f, -2.0f };
    v2f ddA[NPAIR], ddB[NPAIR];
    #pragma unroll
    for (int p = 0; p < NPAIR; ++p) {
        int P = p * 64 + lane;
        float4 q0 = bA[P];
        float4 q1 = bB[P];
        v2f sb2 = ((const v2f*)sSB)[P];
        v2f bx = { q0.x, q0.y }, by = { q0.z, q0.w };
        v2f bz = { q1.x, q1.y }, bw = { q1.z, q1.w };
        v2f d0 = a2v0 * bx;
        d0 = __builtin_elementwise_fma(a3v0, by, d0);
        d0 = __builtin_elementwise_fma(a4v0, bz, d0);
        d0 = __builtin_elementwise_fma(a5v0, bw, d0);
        v2f ss0 = sav0 + sb2;
        ddA[p] = __builtin_elementwise_fma(n2v, d0, ss0);
        v2f d1 = a2v1 * bx;
        d1 = __builtin_elementwise_fma(a3v1, by, d1);
        d1 = __builtin_elementwise_fma(a4v1, bz, d1);
        d1 = __builtin_elementwise_fma(a5v1, bw, d1);
        v2f ss1 = sav1 + sb2;
        ddB[p] = __builtin_elementwise_fma(n2v, d1, ss1);
    }

    if (has0)
        select_row(ddA, a2_0, a3_0, a4_0, a5_0, sa_0, n0, lane, sCidx[wv],
                   bA, bB, sSB, gtab, gumbel, useG, token_src, out);
    if (has1)
        select_row(ddB, a2_1, a3_1, a4_1, a5_1, sa_1, n1, lane, sCidx[wv],
                   bA, bB, sSB, gtab, gumbel, useG, token_src, out);
}

extern "C" void kernel_launch(void* const* d_in, const int* in_sizes, int n_in,
                              void* d_out, int out_size, void* d_ws, size_t ws_size,
                              hipStream_t stream) {
    const float* traj_pos   = (const float*)d_in[0];
    const float* traj_theta = (const float*)d_in[1];
    const float* mpt        = (const float*)d_in[2];
    const float* token_src  = (const float*)d_in[3];
    const float* gumbel     = (const float*)d_in[4];
    float* out = (float*)d_out;

    int N = in_sizes[0] / 6;

    size_t off_bA = 0;                               // 1024 float4 = 16 KB
    size_t off_bB = off_bA + (size_t)(K_TOK/2) * 16; // 16 KB
    size_t off_sb = off_bB + (size_t)(K_TOK/2) * 16; // 8 KB
    size_t off_aA = off_sb + (size_t)K_TOK * 4;      // N*16
    size_t off_sa = off_aA + (size_t)N * 16;         // N*4
    size_t off_g  = off_sa + (size_t)N * 4;          // N*32*4
    size_t need_frame = off_sa + (size_t)N * 4;
    size_t need_g     = off_g + (size_t)N * 32 * 4;

    int useFrame = (ws_size >= need_frame) ? 1 : 0;
    int useG     = (ws_size >= need_g) ? 1 : 0;

    float4* bA  = (float4*)((char*)d_ws + off_bA);
    float4* bB  = (float4*)((char*)d_ws + off_bB);
    float*  sb  = (float*)((char*)d_ws + off_sb);
    float4* aA  = (float4*)((char*)d_ws + off_aA);
    float*  saA = (float*)((char*)d_ws + off_sa);
    float*  g   = (float*)((char*)d_ws + off_g);

    hipLaunchKernelGGL(prep_tok, dim3((K_TOK/2 + 255) / 256), dim3(256), 0, stream, mpt, bA, bB, sb);
    if (useFrame)
        hipLaunchKernelGGL(prep_frame, dim3((N + 255) / 256), dim3(256), 0, stream,
                           traj_pos, traj_theta, aA, saA, N);
    if (useG) {
        int total = N * 32;
        hipLaunchKernelGGL(prep_gumbel, dim3((total + 255) / 256), dim3(256), 0, stream,
                           gumbel, g, total);
    }

    int rows_per_block = WPB * RPW;
    int blocks = (N + rows_per_block - 1) / rows_per_block;
    hipLaunchKernelGGL(topk_kernel, dim3(blocks), dim3(BLK), 0, stream,
                       traj_pos, traj_theta, bA, bB, sb, aA, saA, g,
                       token_src, gumbel, out, N, useFrame, useG);
}

// Round 8
// 270.646 us; speedup vs baseline: 1.5668x; 1.5668x over previous
//
#include <hip/hip_runtime.h>
#include <cstdint>
#include <math.h>

#define K_TOK 2048
#define NPAIR 16      // token pairs per lane (K_TOK / 2 / 64)
#define BLK   256
#define WPB   4       // waves per block
#define RPW   2       // rows per wave -> 8 rows per block

typedef float v2f __attribute__((ext_vector_type(2)));

// monotonic float->uint key (total order == float order, handles negatives)
__device__ __forceinline__ uint32_t f2key(float f) {
    uint32_t u = __float_as_uint(f);
    return u ^ ((uint32_t)(((int32_t)u) >> 31) | 0x80000000u);
}

// ---------------- DPP wave64 primitives (ctrl args constexpr) ----------------
template<int CTRL, int RM, int BM, bool BC>
__device__ __forceinline__ int dpp_i(int old, int v) {
    return __builtin_amdgcn_update_dpp(old, v, CTRL, RM, BM, BC);
}
__device__ __forceinline__ int wave_scan_incl(int v) {
    v += dpp_i<0x111, 0xf, 0xf, true >(0, v);
    v += dpp_i<0x112, 0xf, 0xf, true >(0, v);
    v += dpp_i<0x114, 0xf, 0xf, true >(0, v);
    v += dpp_i<0x118, 0xf, 0xf, true >(0, v);
    v += dpp_i<0x142, 0xa, 0xf, false>(0, v);
    v += dpp_i<0x143, 0xc, 0xf, false>(0, v);
    return v;
}
template<int M>
__device__ __forceinline__ uint32_t lxu(uint32_t x) {
    if constexpr (M == 1)       return (uint32_t)dpp_i<0xB1,  0xf, 0xf, true>(0, (int)x);
    else if constexpr (M == 2)  return (uint32_t)dpp_i<0x4E,  0xf, 0xf, true>(0, (int)x);
    else if constexpr (M == 8)  return (uint32_t)dpp_i<0x128, 0xf, 0xf, true>(0, (int)x);
    else if constexpr (M == 4)  return (uint32_t)__builtin_amdgcn_ds_swizzle((int)x, 0x101F);
    else if constexpr (M == 16) return (uint32_t)__builtin_amdgcn_ds_swizzle((int)x, 0x401F);
    else                        return (uint32_t)__shfl_xor((int)x, 32, 64);
}
template<int M>
__device__ __forceinline__ uint64_t lxu64(uint64_t x) {
    uint32_t h = lxu<M>((uint32_t)(x >> 32));
    uint32_t l = lxu<M>((uint32_t)x);
    return ((uint64_t)h << 32) | l;
}

// ---------------- prep kernels ----------------
// Split pair streams: bA[P] = {b2[2P],b2[2P+1],b3[2P],b3[2P+1]},
//                     bB[P] = {b4[2P],b4[2P+1],b5[2P],b5[2P+1]}
__global__ void prep_tok(const float* __restrict__ mpt,
                         float4* __restrict__ bA, float4* __restrict__ bB,
                         float* __restrict__ sbout) {
    #pragma clang fp contract(off)
    int P = blockIdx.x * blockDim.x + threadIdx.x;
    if (P >= K_TOK / 2) return;
    int k0 = 2 * P, k1 = 2 * P + 1;
    float u0 = mpt[k0*6+0], u1 = mpt[k0*6+1], u2 = mpt[k0*6+2];
    float u3 = mpt[k0*6+3], u4 = mpt[k0*6+4], u5 = mpt[k0*6+5];
    float w0 = mpt[k1*6+0], w1 = mpt[k1*6+1], w2 = mpt[k1*6+2];
    float w3 = mpt[k1*6+3], w4 = mpt[k1*6+4], w5 = mpt[k1*6+5];
    float s0 = ((((u0*u0+u1*u1)+u2*u2)+u3*u3)+u4*u4)+u5*u5;
    float s1 = ((((w0*w0+w1*w1)+w2*w2)+w3*w3)+w4*w4)+w5*w5;
    bA[P] = make_float4(u2, w2, u3, w3);
    bB[P] = make_float4(u4, w4, u5, w5);
    sbout[k0] = s0; sbout[k1] = s1;
}

__global__ void prep_frame(const float* __restrict__ traj_pos,
                           const float* __restrict__ traj_theta,
                           float4* __restrict__ aA, float* __restrict__ saA, int N) {
    #pragma clang fp contract(off)
    int n = blockIdx.x * blockDim.x + threadIdx.x;
    if (n >= N) return;
    const float* tp = traj_pos + (size_t)n*6;
    float p0x=tp[0], p0y=tp[1];
    float dx1=tp[2]-p0x, dy1=tp[3]-p0y;
    float dx2=tp[4]-p0x, dy2=tp[5]-p0y;
    float th = traj_theta[n];
    float c = (float)cos((double)th);
    float s = (float)sin((double)th);
    float ns = -s;
    float a2 = c*dx1 + s*dy1;
    float a3 = ns*dx1 + c*dy1;
    float a4 = c*dx2 + s*dy2;
    float a5 = ns*dx2 + c*dy2;
    float q2=a2*a2,q3=a3*a3,q4=a4*a4,q5=a5*a5;
    float sa = ((q2+q3)+q4)+q5;
    aA[n] = make_float4(a2,a3,a4,a5);
    saA[n] = sa;
}

__global__ void prep_gumbel(const float* __restrict__ gu, float* __restrict__ g, int total) {
    #pragma clang fp contract(off)
    int i = blockIdx.x * blockDim.x + threadIdx.x;
    if (i >= total) return;
    const float C1F = (float)(1.0 - 2.0*1e-7);
    float u = gu[i];
    float t = u * C1F;
    t = t + 1e-7f;
    float li = (float)log((double)t);
    float ni = -li;
    float lo = (float)log((double)ni);
    g[i] = -lo;
}

// wave-uniform count via ballot (v_cmp on VALU, bcnt/add on SALU pipe)
__device__ __forceinline__ int count_le_sc(const v2f (&dd)[NPAIR], float T) {
    int c = 0;
    #pragma unroll
    for (int p = 0; p < NPAIR; ++p) {
        c += (int)__popcll(__ballot(dd[p].x <= T));
        c += (int)__popcll(__ballot(dd[p].y <= T));
    }
    return c;
}
__device__ __forceinline__ int count_key_sc(const v2f (&dd)[NPAIR], uint32_t A) {
    int c = 0;
    #pragma unroll
    for (int p = 0; p < NPAIR; ++p) {
        c += (int)__popcll(__ballot(f2key(dd[p].x) <= A));
        c += (int)__popcll(__ballot(f2key(dd[p].y) <= A));
    }
    return c;
}

// ---------------- per-row selection (inlined; dd bound statically) ----------------
__device__ __forceinline__ void select_row(
        const v2f (&dd)[NPAIR], float a2, float a3, float a4, float a5, float sa,
        int n, int lane, uint32_t* sCrow,
        const float4* __restrict__ bA, const float4* __restrict__ bB,
        const float* __restrict__ sSB,
        const float* __restrict__ gtab, const float* __restrict__ gumbel, int useG,
        const float* __restrict__ token_src, float* __restrict__ out) {
    #pragma clang fp contract(off)
    // per-lane min
    float lmin = INFINITY;
    #pragma unroll
    for (int p = 0; p < NPAIR; ++p) {
        lmin = fminf(lmin, dd[p].x);
        lmin = fminf(lmin, dd[p].y);
    }
    // bitonic ascending sort of lane minima -> order stats
    {
        float v = lmin;
        #define FST(K2,J2) { float o = __uint_as_float(lxu<J2>(__float_as_uint(v))); \
            bool up = ((lane & K2) == 0) == ((lane & J2) == 0); \
            v = up ? fminf(v, o) : fmaxf(v, o); }
        FST(2,1)
        FST(4,2)  FST(4,1)
        FST(8,4)  FST(8,2)  FST(8,1)
        FST(16,8) FST(16,4) FST(16,2) FST(16,1)
        FST(32,16) FST(32,8) FST(32,4) FST(32,2) FST(32,1)
        FST(64,32) FST(64,16) FST(64,8) FST(64,4) FST(64,2) FST(64,1)
        #undef FST
        lmin = v;
    }
    float gmn = __uint_as_float((uint32_t)__builtin_amdgcn_readlane((int)__float_as_uint(lmin), 0));
    float T0  = __uint_as_float((uint32_t)__builtin_amdgcn_readlane((int)__float_as_uint(lmin), 31));

    // threshold with count(d <= T) in [32,64]; counts land on scalar pipe
    float T = T0;
    int cnt = count_le_sc(dd, T0);
    bool done = (cnt >= 32 && cnt <= 64);
    float loV = gmn, hiV = T0;
    for (int it = 0; it < 12 && !done; ++it) {
        float mid = 0.5f * (loV + hiV);
        if (!(mid > loV && mid < hiV)) break;
        int c = count_le_sc(dd, mid);
        if (c < 32) loV = mid;
        else if (c > 64) hiV = mid;
        else { cnt = c; T = mid; done = true; }
    }
    uint32_t A = 0u;
    bool useKey = false;
    if (!done) {
        // exact bitwise binary search fallback (cold, provably correct)
        bool found = false; int ccf = 0;
        for (int b = 31; b >= 0; --b) {
            uint32_t T2 = A | ((1u << b) - 1u);
            int cc = count_key_sc(dd, T2);
            if (cc >= 32) { if (cc <= 64) { A = T2; ccf = cc; found = true; break; } }
            else A |= (1u << b);
        }
        if (!found) ccf = count_key_sc(dd, A);
        cnt = ccf;
        useKey = true;
    }
    int cnt_cap = cnt > 64 ? 64 : cnt;

    // per-lane candidate mask at the accepted threshold
    uint32_t cmask = 0;
    if (!useKey) {
        #pragma unroll
        for (int p = 0; p < NPAIR; ++p) {
            if (dd[p].x <= T) cmask |= (1u << (2*p));
            if (dd[p].y <= T) cmask |= (1u << (2*p+1));
        }
    } else {
        #pragma unroll
        for (int p = 0; p < NPAIR; ++p) {
            if (f2key(dd[p].x) <= A) cmask |= (1u << (2*p));
            if (f2key(dd[p].y) <= A) cmask |= (1u << (2*p+1));
        }
    }

    // sparse compaction: store token index only
    {
        int lc  = __popc(cmask);
        int pos = wave_scan_incl(lc) - lc;   // exclusive prefix
        uint32_t m = cmask;
        while (m) {
            int j = __builtin_ctz(m);
            m &= m - 1;
            int token = 2 * ((j >> 1) * 64 + lane) + (j & 1);
            if (pos < 64) sCrow[pos] = (uint32_t)token;
            ++pos;
        }
    }
    asm volatile("s_waitcnt lgkmcnt(0)" ::: "memory");

    // read back + exact recompute (identical op sequence -> identical bits)
    uint64_t bv;
    if (lane < cnt_cap) {
        uint32_t idxv = sCrow[lane];
        uint32_t P = idxv >> 1;
        float4 q0 = bA[P];
        float4 q1 = bB[P];
        int h = (int)(idxv & 1u);
        float bx = h ? q0.y : q0.x;
        float by = h ? q0.w : q0.z;
        float bz = h ? q1.y : q1.x;
        float bw = h ? q1.w : q1.z;
        float sbv = sSB[idxv];
        float d0 = a2 * bx;
        d0 = fmaf(a3, by, d0);
        d0 = fmaf(a4, bz, d0);
        d0 = fmaf(a5, bw, d0);
        float ss = sa + sbv;
        float dist = fmaf(-2.0f, d0, ss);
        bv = ((uint64_t)f2key(dist) << 16) | (uint64_t)idxv;
    } else {
        bv = ~0ull;
    }

    // bitonic sort of 64 candidates, ascending (key,idx); slot l -> lane l
    #define UST(K2,J2) { uint64_t o = lxu64<J2>(bv); \
        bool up = ((lane & K2) == 0) == ((lane & J2) == 0); \
        bv = ((o < bv) == up) ? o : bv; }
    UST(2,1)
    UST(4,2)  UST(4,1)
    UST(8,4)  UST(8,2)  UST(8,1)
    UST(16,8) UST(16,4) UST(16,2) UST(16,1)
    UST(32,16) UST(32,8) UST(32,4) UST(32,2) UST(32,1)
    UST(64,32) UST(64,16) UST(64,8) UST(64,4) UST(64,2) UST(64,1)
    #undef UST

    // gumbel-argmax over 32 sorted slots (tie -> lower slot)
    float dsel;
    {
        uint32_t kbits = (uint32_t)(bv >> 16);
        uint32_t mkb = ((uint32_t)((~(int32_t)kbits) >> 31)) | 0x80000000u;
        dsel = __uint_as_float(kbits ^ mkb);
    }
    int tok = (int)(bv & 0xFFFFu);
    uint32_t kh = 0u, kl = 0u;
    if (lane < 32) {
        float neg   = -dsel;
        float logit = (-1e-6f) + neg;
        float g;
        if (useG) {
            g = gtab[(size_t)n * 32 + lane];
        } else {
            const float C1F = (float)(1.0 - 2.0 * 1e-7);
            float u = gumbel[(size_t)n * 32 + lane];
            float t = u * C1F;
            t = t + 1e-7f;
            float li = (float)log((double)t);
            float ni = -li;
            float lo2 = (float)log((double)ni);
            g = -lo2;
        }
        float score = logit + g;
        kh = f2key(score);
        kl = ((uint32_t)(63 - lane) << 11) | (uint32_t)tok;  // tie -> lower slot
    }
    #define MAXST(CTRL, RM) { \
        uint32_t oh = (uint32_t)dpp_i<CTRL, RM, 0xf, false>((int)kh, (int)kh); \
        uint32_t ol = (uint32_t)dpp_i<CTRL, RM, 0xf, false>((int)kl, (int)kl); \
        if (((((uint64_t)oh << 32) | ol)) > ((((uint64_t)kh << 32) | kl))) { kh = oh; kl = ol; } }
    MAXST(0x111, 0xf) MAXST(0x112, 0xf) MAXST(0x114, 0xf) MAXST(0x118, 0xf)
    MAXST(0x142, 0xa) MAXST(0x143, 0xc)
    #undef MAXST
    uint32_t wl = (uint32_t)__builtin_amdgcn_readlane((int)kl, 63);
    int tw = (int)(wl & 0x7FFu);

    if (lane < 22) out[(size_t)n * 22 + lane] = token_src[(size_t)tw * 22 + lane];
}

// ---------------- main kernel ----------------
__global__ __launch_bounds__(BLK) void topk_kernel(
        const float* __restrict__ traj_pos, const float* __restrict__ traj_theta,
        const float4* __restrict__ bA, const float4* __restrict__ bB,
        const float* __restrict__ sbg,
        const float4* __restrict__ aAg, const float* __restrict__ saAg,
        const float* __restrict__ gtab,
        const float* __restrict__ token_src, const float* __restrict__ gumbel,
        float* __restrict__ out, int Nrows, int useFrame, int useG) {
    #pragma clang fp contract(off)
    __shared__ float    sSB[K_TOK];            // 8 KB
    __shared__ uint32_t sCidx[WPB][64];        // 1 KB

    const int tid = threadIdx.x;
    {
        const float4* s4 = (const float4*)sbg;
        #pragma unroll
        for (int r = 0; r < 2; ++r)
            ((float4*)sSB)[tid + r * BLK] = s4[tid + r * BLK];   // 8 KB staged
    }
    __syncthreads();

    const int wv   = tid >> 6;
    const int lane = tid & 63;
    const int n0   = blockIdx.x * (WPB * RPW) + wv;       // row 0 of this wave
    const int n1   = n0 + WPB;                            // row 1 of this wave

    // ---- frames for both rows
    float a2_0=0, a3_0=0, a4_0=0, a5_0=0, sa_0=0;
    float a2_1=0, a3_1=0, a4_1=0, a5_1=0, sa_1=0;
    bool has0 = (n0 < Nrows), has1 = (n1 < Nrows);
    if (useFrame) {
        if (has0) { float4 av = aAg[n0]; a2_0=av.x; a3_0=av.y; a4_0=av.z; a5_0=av.w; sa_0=saAg[n0]; }
        if (has1) { float4 av = aAg[n1]; a2_1=av.x; a3_1=av.y; a4_1=av.z; a5_1=av.w; sa_1=saAg[n1]; }
    } else {
        for (int r = 0; r < 2; ++r) {
            int n = r ? n1 : n0;
            if (n >= Nrows) continue;
            const float* tp = traj_pos + (size_t)n * 6;
            float p0x = tp[0], p0y = tp[1];
            float dx1 = tp[2] - p0x, dy1 = tp[3] - p0y;
            float dx2 = tp[4] - p0x, dy2 = tp[5] - p0y;
            float th = traj_theta[n];
            float c = (float)cos((double)th);
            float s = (float)sin((double)th);
            float ns = -s;
            float a2 = c*dx1 + s*dy1;
            float a3 = ns*dx1 + c*dy1;
            float a4 = c*dx2 + s*dy2;
            float a5 = ns*dx2 + c*dy2;
            float q2 = a2*a2, q3 = a3*a3, q4 = a4*a4, q5 = a5*a5;
            float sa = ((q2 + q3) + q4) + q5;
            if (r) { a2_1=a2; a3_1=a3; a4_1=a4; a5_1=a5; sa_1=sa; }
            else   { a2_0=a2; a3_0=a3; a4_0=a4; a5_0=a5; sa_0=sa; }
        }
    }

    // ---- shared-B packed distance loop for both rows
    const v2f a2v0={a2_0,a2_0}, a3v0={a3_0,a3_0}, a4v0={a4_0,a4_0}, a5v0={a5_0,a5_0}, sav0={sa_0,sa_0};
    const v2f a2v1={a2_1,a2_1}, a3v1={a3_1,a3_1}, a4v1={a4_1,a4_1}, a5v1={a5_1,a5_1}, sav1={sa_1,sa_1};
    const v2f n2v = { -2.0f, -2.0f };
    v2f ddA[NPAIR], ddB[NPAIR];
    #pragma unroll
    for (int p = 0; p < NPAIR; ++p) {
        int P = p * 64 + lane;
        float4 q0 = bA[P];
        float4 q1 = bB[P];
        v2f sb2 = ((const v2f*)sSB)[P];
        v2f bx = { q0.x, q0.y }, by = { q0.z, q0.w };
        v2f bz = { q1.x, q1.y }, bw = { q1.z, q1.w };
        v2f d0 = a2v0 * bx;
        d0 = __builtin_elementwise_fma(a3v0, by, d0);
        d0 = __builtin_elementwise_fma(a4v0, bz, d0);
        d0 = __builtin_elementwise_fma(a5v0, bw, d0);
        v2f ss0 = sav0 + sb2;
        ddA[p] = __builtin_elementwise_fma(n2v, d0, ss0);
        v2f d1 = a2v1 * bx;
        d1 = __builtin_elementwise_fma(a3v1, by, d1);
        d1 = __builtin_elementwise_fma(a4v1, bz, d1);
        d1 = __builtin_elementwise_fma(a5v1, bw, d1);
        v2f ss1 = sav1 + sb2;
        ddB[p] = __builtin_elementwise_fma(n2v, d1, ss1);
    }

    if (has0)
        select_row(ddA, a2_0, a3_0, a4_0, a5_0, sa_0, n0, lane, sCidx[wv],
                   bA, bB, sSB, gtab, gumbel, useG, token_src, out);
    if (has1)
        select_row(ddB, a2_1, a3_1, a4_1, a5_1, sa_1, n1, lane, sCidx[wv],
                   bA, bB, sSB, gtab, gumbel, useG, token_src, out);
}

extern "C" void kernel_launch(void* const* d_in, const int* in_sizes, int n_in,
                              void* d_out, int out_size, void* d_ws, size_t ws_size,
                              hipStream_t stream) {
    const float* traj_pos   = (const float*)d_in[0];
    const float* traj_theta = (const float*)d_in[1];
    const float* mpt        = (const float*)d_in[2];
    const float* token_src  = (const float*)d_in[3];
    const float* gumbel     = (const float*)d_in[4];
    float* out = (float*)d_out;

    int N = in_sizes[0] / 6;

    size_t off_bA = 0;                               // 1024 float4 = 16 KB
    size_t off_bB = off_bA + (size_t)(K_TOK/2) * 16; // 16 KB
    size_t off_sb = off_bB + (size_t)(K_TOK/2) * 16; // 8 KB
    size_t off_aA = off_sb + (size_t)K_TOK * 4;      // N*16
    size_t off_sa = off_aA + (size_t)N * 16;         // N*4
    size_t off_g  = off_sa + (size_t)N * 4;          // N*32*4
    size_t need_frame = off_sa + (size_t)N * 4;
    size_t need_g     = off_g + (size_t)N * 32 * 4;

    int useFrame = (ws_size >= need_frame) ? 1 : 0;
    int useG     = (ws_size >= need_g) ? 1 : 0;

    float4* bA  = (float4*)((char*)d_ws + off_bA);
    float4* bB  = (float4*)((char*)d_ws + off_bB);
    float*  sb  = (float*)((char*)d_ws + off_sb);
    float4* aA  = (float4*)((char*)d_ws + off_aA);
    float*  saA = (float*)((char*)d_ws + off_sa);
    float*  g   = (float*)((char*)d_ws + off_g);

    hipLaunchKernelGGL(prep_tok, dim3((K_TOK/2 + 255) / 256), dim3(256), 0, stream, mpt, bA, bB, sb);
    if (useFrame)
        hipLaunchKernelGGL(prep_frame, dim3((N + 255) / 256), dim3(256), 0, stream,
                           traj_pos, traj_theta, aA, saA, N);
    if (useG) {
        int total = N * 32;
        hipLaunchKernelGGL(prep_gumbel, dim3((total + 255) / 256), dim3(256), 0, stream,
                           gumbel, g, total);
    }

    int rows_per_block = WPB * RPW;
    int blocks = (N + rows_per_block - 1) / rows_per_block;
    hipLaunchKernelGGL(topk_kernel, dim3(blocks), dim3(BLK), 0, stream,
                       traj_pos, traj_theta, bA, bB, sb, aA, saA, g,
                       token_src, gumbel, out, N, useFrame, useG);
}

// Round 9
// 129.787 us; speedup vs baseline: 3.2672x; 2.0853x over previous
//
#include <hip/hip_runtime.h>
#include <cstdint>
#include <math.h>

#define K_TOK 2048
#define NPAIR 16      // token pairs per lane (K_TOK / 2 / 64)
#define BLK   512
#define WPB   8       // waves (=rows) per block, 1 row per wave

typedef float v2f __attribute__((ext_vector_type(2)));

// monotonic float->uint key (total order == float order, handles negatives)
__device__ __forceinline__ uint32_t f2key(float f) {
    uint32_t u = __float_as_uint(f);
    return u ^ ((uint32_t)(((int32_t)u) >> 31) | 0x80000000u);
}

// ---------------- DPP wave64 primitives (ctrl args constexpr) ----------------
template<int CTRL, int RM, int BM, bool BC>
__device__ __forceinline__ int dpp_i(int old, int v) {
    return __builtin_amdgcn_update_dpp(old, v, CTRL, RM, BM, BC);
}
__device__ __forceinline__ int wave_scan_incl(int v) {
    v += dpp_i<0x111, 0xf, 0xf, true >(0, v);
    v += dpp_i<0x112, 0xf, 0xf, true >(0, v);
    v += dpp_i<0x114, 0xf, 0xf, true >(0, v);
    v += dpp_i<0x118, 0xf, 0xf, true >(0, v);
    v += dpp_i<0x142, 0xa, 0xf, false>(0, v);
    v += dpp_i<0x143, 0xc, 0xf, false>(0, v);
    return v;
}
template<int M>
__device__ __forceinline__ uint32_t lxu(uint32_t x) {
    if constexpr (M == 1)       return (uint32_t)dpp_i<0xB1,  0xf, 0xf, true>(0, (int)x);
    else if constexpr (M == 2)  return (uint32_t)dpp_i<0x4E,  0xf, 0xf, true>(0, (int)x);
    else if constexpr (M == 8)  return (uint32_t)dpp_i<0x128, 0xf, 0xf, true>(0, (int)x);
    else if constexpr (M == 4)  return (uint32_t)__builtin_amdgcn_ds_swizzle((int)x, 0x101F);
    else if constexpr (M == 16) return (uint32_t)__builtin_amdgcn_ds_swizzle((int)x, 0x401F);
    else                        return (uint32_t)__shfl_xor((int)x, 32, 64);
}
template<int M>
__device__ __forceinline__ uint64_t lxu64(uint64_t x) {
    uint32_t h = lxu<M>((uint32_t)(x >> 32));
    uint32_t l = lxu<M>((uint32_t)x);
    return ((uint64_t)h << 32) | l;
}

// ---------------- prep kernels (validated bit-exact R1-R8) ----------------
// Split pair streams: bA[P] = {b2[2P],b2[2P+1],b3[2P],b3[2P+1]},
//                     bB[P] = {b4[2P],b4[2P+1],b5[2P],b5[2P+1]}
__global__ void prep_tok(const float* __restrict__ mpt,
                         float4* __restrict__ bA, float4* __restrict__ bB,
                         float* __restrict__ sbout) {
    #pragma clang fp contract(off)
    int P = blockIdx.x * blockDim.x + threadIdx.x;
    if (P >= K_TOK / 2) return;
    int k0 = 2 * P, k1 = 2 * P + 1;
    float u0 = mpt[k0*6+0], u1 = mpt[k0*6+1], u2 = mpt[k0*6+2];
    float u3 = mpt[k0*6+3], u4 = mpt[k0*6+4], u5 = mpt[k0*6+5];
    float w0 = mpt[k1*6+0], w1 = mpt[k1*6+1], w2 = mpt[k1*6+2];
    float w3 = mpt[k1*6+3], w4 = mpt[k1*6+4], w5 = mpt[k1*6+5];
    float s0 = ((((u0*u0+u1*u1)+u2*u2)+u3*u3)+u4*u4)+u5*u5;
    float s1 = ((((w0*w0+w1*w1)+w2*w2)+w3*w3)+w4*w4)+w5*w5;
    bA[P] = make_float4(u2, w2, u3, w3);
    bB[P] = make_float4(u4, w4, u5, w5);
    sbout[k0] = s0; sbout[k1] = s1;
}

__global__ void prep_frame(const float* __restrict__ traj_pos,
                           const float* __restrict__ traj_theta,
                           float4* __restrict__ aA, float* __restrict__ saA, int N) {
    #pragma clang fp contract(off)
    int n = blockIdx.x * blockDim.x + threadIdx.x;
    if (n >= N) return;
    const float* tp = traj_pos + (size_t)n*6;
    float p0x=tp[0], p0y=tp[1];
    float dx1=tp[2]-p0x, dy1=tp[3]-p0y;
    float dx2=tp[4]-p0x, dy2=tp[5]-p0y;
    float th = traj_theta[n];
    float c = (float)cos((double)th);
    float s = (float)sin((double)th);
    float ns = -s;
    float a2 = c*dx1 + s*dy1;
    float a3 = ns*dx1 + c*dy1;
    float a4 = c*dx2 + s*dy2;
    float a5 = ns*dx2 + c*dy2;
    float q2=a2*a2,q3=a3*a3,q4=a4*a4,q5=a5*a5;
    float sa = ((q2+q3)+q4)+q5;
    aA[n] = make_float4(a2,a3,a4,a5);
    saA[n] = sa;
}

__global__ void prep_gumbel(const float* __restrict__ gu, float* __restrict__ g, int total) {
    #pragma clang fp contract(off)
    int i = blockIdx.x * blockDim.x + threadIdx.x;
    if (i >= total) return;
    const float C1F = (float)(1.0 - 2.0*1e-7);
    float u = gu[i];
    float t = u * C1F;
    t = t + 1e-7f;
    float li = (float)log((double)t);
    float ni = -li;
    float lo = (float)log((double)ni);
    g[i] = -lo;
}

// wave-uniform counts via ballot: v_cmp on VALU, bcnt/add on SALU pipe
__device__ __forceinline__ int count_le_sc(const v2f (&dd)[NPAIR], float T) {
    int c = 0;
    #pragma unroll
    for (int p = 0; p < NPAIR; ++p) {
        c += (int)__popcll(__ballot(dd[p].x <= T));
        c += (int)__popcll(__ballot(dd[p].y <= T));
    }
    return c;
}
__device__ __forceinline__ int count_key_sc(const v2f (&dd)[NPAIR], uint32_t A) {
    int c = 0;
    #pragma unroll
    for (int p = 0; p < NPAIR; ++p) {
        c += (int)__popcll(__ballot(f2key(dd[p].x) <= A));
        c += (int)__popcll(__ballot(f2key(dd[p].y) <= A));
    }
    return c;
}

// ---------------- main kernel (R6 structure: 1 row per wave) ----------------
__global__ __launch_bounds__(BLK, 4) void topk_kernel(
        const float* __restrict__ traj_pos, const float* __restrict__ traj_theta,
        const float4* __restrict__ bA, const float4* __restrict__ bB,
        const float* __restrict__ sbg,
        const float4* __restrict__ aAg, const float* __restrict__ saAg,
        const float* __restrict__ gtab,
        const float* __restrict__ token_src, const float* __restrict__ gumbel,
        float* __restrict__ out, int Nrows, int useFrame, int useG) {
    #pragma clang fp contract(off)
    __shared__ float    sSB[K_TOK];            // 8 KB
    __shared__ uint32_t sCidx[WPB][64];        // 2 KB

    const int tid = threadIdx.x;
    {
        const float4* s4 = (const float4*)sbg;
        ((float4*)sSB)[tid] = s4[tid];         // 8 KB staged
    }
    __syncthreads();

    const int wv   = tid >> 6;
    const int lane = tid & 63;
    const int n    = blockIdx.x * WPB + wv;
    if (n >= Nrows) return;

    // ---- per-row local frame
    float a2, a3, a4, a5, sa;
    if (useFrame) {
        float4 av = aAg[n];
        a2 = av.x; a3 = av.y; a4 = av.z; a5 = av.w;
        sa = saAg[n];
    } else {
        const float* tp = traj_pos + (size_t)n * 6;
        float p0x = tp[0], p0y = tp[1];
        float dx1 = tp[2] - p0x, dy1 = tp[3] - p0y;
        float dx2 = tp[4] - p0x, dy2 = tp[5] - p0y;
        float th = traj_theta[n];
        float c = (float)cos((double)th);
        float s = (float)sin((double)th);
        float ns = -s;
        a2 = c*dx1 + s*dy1;
        a3 = ns*dx1 + c*dy1;
        a4 = c*dx2 + s*dy2;
        a5 = ns*dx2 + c*dy2;
        float q2 = a2*a2, q3 = a3*a3, q4 = a4*a4, q5 = a5*a5;
        sa = ((q2 + q3) + q4) + q5;
    }

    // ---- packed distances (per-component rounding == validated scalar chain)
    const v2f a2v = { a2, a2 }, a3v = { a3, a3 }, a4v = { a4, a4 }, a5v = { a5, a5 };
    const v2f sav = { sa, sa }, n2v = { -2.0f, -2.0f };
    v2f dd2[NPAIR];
    v2f lm2 = { INFINITY, INFINITY };
    #pragma unroll
    for (int p = 0; p < NPAIR; ++p) {
        int P = p * 64 + lane;
        float4 q0 = bA[P];
        float4 q1 = bB[P];
        v2f sb2 = ((const v2f*)sSB)[P];
        v2f bx = { q0.x, q0.y }, by = { q0.z, q0.w };
        v2f bz = { q1.x, q1.y }, bw = { q1.z, q1.w };
        v2f d = a2v * bx;
        d = __builtin_elementwise_fma(a3v, by, d);
        d = __builtin_elementwise_fma(a4v, bz, d);
        d = __builtin_elementwise_fma(a5v, bw, d);
        v2f ss = sav + sb2;
        v2f dist = __builtin_elementwise_fma(n2v, d, ss);
        dd2[p] = dist;
        lm2.x = fminf(lm2.x, dist.x);
        lm2.y = fminf(lm2.y, dist.y);
    }
    float lmin = fminf(lm2.x, lm2.y);

    // ---- bitonic ascending sort of lane minima (T0 = 31st order stat)
    {
        float v = lmin;
        #define FST(K2,J2) { float o = __uint_as_float(lxu<J2>(__float_as_uint(v))); \
            bool up = ((lane & K2) == 0) == ((lane & J2) == 0); \
            v = up ? fminf(v, o) : fmaxf(v, o); }
        FST(2,1)
        FST(4,2)  FST(4,1)
        FST(8,4)  FST(8,2)  FST(8,1)
        FST(16,8) FST(16,4) FST(16,2) FST(16,1)
        FST(32,16) FST(32,8) FST(32,4) FST(32,2) FST(32,1)
        FST(64,32) FST(64,16) FST(64,8) FST(64,4) FST(64,2) FST(64,1)
        #undef FST
        lmin = v;
    }
    float gmn = __uint_as_float((uint32_t)__builtin_amdgcn_readlane((int)__float_as_uint(lmin), 0));
    float T0  = __uint_as_float((uint32_t)__builtin_amdgcn_readlane((int)__float_as_uint(lmin), 31));

    // ---- threshold with count(d <= T) in [32,64]; counts via ballot/SALU
    float T = T0;
    int cnt = count_le_sc(dd2, T0);
    bool done = (cnt >= 32 && cnt <= 64);
    float loV = gmn, hiV = T0;
    for (int it = 0; it < 12 && !done; ++it) {
        float mid = 0.5f * (loV + hiV);
        if (!(mid > loV && mid < hiV)) break;
        int c = count_le_sc(dd2, mid);
        if (c < 32) loV = mid;
        else if (c > 64) hiV = mid;
        else { cnt = c; T = mid; done = true; }
    }
    uint32_t A = 0u;
    bool useKey = false;
    if (!done) {
        // exact bitwise binary search fallback (cold, provably correct)
        bool found = false; int ccf = 0;
        for (int b = 31; b >= 0; --b) {
            uint32_t T2 = A | ((1u << b) - 1u);
            int cc = count_key_sc(dd2, T2);
            if (cc >= 32) { if (cc <= 64) { A = T2; ccf = cc; found = true; break; } }
            else A |= (1u << b);
        }
        if (!found) ccf = count_key_sc(dd2, A);
        cnt = ccf;
        useKey = true;
    }
    int cnt_cap = cnt > 64 ? 64 : cnt;

    // ---- per-lane candidate mask at the accepted threshold (built once)
    uint32_t cmask = 0;
    if (!useKey) {
        #pragma unroll
        for (int p = 0; p < NPAIR; ++p) {
            if (dd2[p].x <= T) cmask |= (1u << (2*p));
            if (dd2[p].y <= T) cmask |= (1u << (2*p+1));
        }
    } else {
        #pragma unroll
        for (int p = 0; p < NPAIR; ++p) {
            if (f2key(dd2[p].x) <= A) cmask |= (1u << (2*p));
            if (f2key(dd2[p].y) <= A) cmask |= (1u << (2*p+1));
        }
    }

    // ---- sparse compaction: store token index only (E[iters/lane] ~ 0.7)
    {
        int lc  = __popc(cmask);
        int pos = wave_scan_incl(lc) - lc;   // exclusive prefix
        uint32_t m = cmask;
        while (m) {
            int j = __builtin_ctz(m);
            m &= m - 1;
            int token = 2 * ((j >> 1) * 64 + lane) + (j & 1);
            if (pos < 64) sCidx[wv][pos] = (uint32_t)token;
            ++pos;
        }
    }
    asm volatile("s_waitcnt lgkmcnt(0)" ::: "memory");

    // ---- read back + exact recompute (identical op sequence -> identical bits)
    uint64_t bv;
    if (lane < cnt_cap) {
        uint32_t idxv = sCidx[wv][lane];
        uint32_t P = idxv >> 1;
        float4 q0 = bA[P];
        float4 q1 = bB[P];
        int h = (int)(idxv & 1u);
        float bx = h ? q0.y : q0.x;
        float by = h ? q0.w : q0.z;
        float bz = h ? q1.y : q1.x;
        float bw = h ? q1.w : q1.z;
        float sbv = sSB[idxv];
        float d0 = a2 * bx;
        d0 = fmaf(a3, by, d0);
        d0 = fmaf(a4, bz, d0);
        d0 = fmaf(a5, bw, d0);
        float ss = sa + sbv;
        float dist = fmaf(-2.0f, d0, ss);
        bv = ((uint64_t)f2key(dist) << 16) | (uint64_t)idxv;
    } else {
        bv = ~0ull;
    }

    // ---- bitonic sort of 64 candidates, ascending (key,idx); slot l -> lane l
    #define UST(K2,J2) { uint64_t o = lxu64<J2>(bv); \
        bool up = ((lane & K2) == 0) == ((lane & J2) == 0); \
        bv = ((o < bv) == up) ? o : bv; }
    UST(2,1)
    UST(4,2)  UST(4,1)
    UST(8,4)  UST(8,2)  UST(8,1)
    UST(16,8) UST(16,4) UST(16,2) UST(16,1)
    UST(32,16) UST(32,8) UST(32,4) UST(32,2) UST(32,1)
    UST(64,32) UST(64,16) UST(64,8) UST(64,4) UST(64,2) UST(64,1)
    #undef UST

    // ---- gumbel-argmax over 32 sorted slots (tie -> lower slot)
    float dsel;
    {
        uint32_t kbits = (uint32_t)(bv >> 16);
        uint32_t mkb = ((uint32_t)((~(int32_t)kbits) >> 31)) | 0x80000000u;
        dsel = __uint_as_float(kbits ^ mkb);
    }
    int tok = (int)(bv & 0xFFFFu);
    uint32_t kh = 0u, kl = 0u;
    if (lane < 32) {
        float neg   = -dsel;
        float logit = (-1e-6f) + neg;
        float g;
        if (useG) {
            g = gtab[(size_t)n * 32 + lane];
        } else {
            const float C1F = (float)(1.0 - 2.0 * 1e-7);
            float u = gumbel[(size_t)n * 32 + lane];
            float t = u * C1F;
            t = t + 1e-7f;
            float li = (float)log((double)t);
            float ni = -li;
            float lo2 = (float)log((double)ni);
            g = -lo2;
        }
        float score = logit + g;
        kh = f2key(score);
        kl = ((uint32_t)(63 - lane) << 11) | (uint32_t)tok;  // tie -> lower slot
    }
    #define MAXST(CTRL, RM) { \
        uint32_t oh = (uint32_t)dpp_i<CTRL, RM, 0xf, false>((int)kh, (int)kh); \
        uint32_t ol = (uint32_t)dpp_i<CTRL, RM, 0xf, false>((int)kl, (int)kl); \
        if (((((uint64_t)oh << 32) | ol)) > ((((uint64_t)kh << 32) | kl))) { kh = oh; kl = ol; } }
    MAXST(0x111, 0xf) MAXST(0x112, 0xf) MAXST(0x114, 0xf) MAXST(0x118, 0xf)
    MAXST(0x142, 0xa) MAXST(0x143, 0xc)
    #undef MAXST
    uint32_t wl = (uint32_t)__builtin_amdgcn_readlane((int)kl, 63);
    int tw = (int)(wl & 0x7FFu);

    if (lane < 22) out[(size_t)n * 22 + lane] = token_src[(size_t)tw * 22 + lane];
}

extern "C" void kernel_launch(void* const* d_in, const int* in_sizes, int n_in,
                              void* d_out, int out_size, void* d_ws, size_t ws_size,
                              hipStream_t stream) {
    const float* traj_pos   = (const float*)d_in[0];
    const float* traj_theta = (const float*)d_in[1];
    const float* mpt        = (const float*)d_in[2];
    const float* token_src  = (const float*)d_in[3];
    const float* gumbel     = (const float*)d_in[4];
    float* out = (float*)d_out;

    int N = in_sizes[0] / 6;

    size_t off_bA = 0;                               // 1024 float4 = 16 KB
    size_t off_bB = off_bA + (size_t)(K_TOK/2) * 16; // 16 KB
    size_t off_sb = off_bB + (size_t)(K_TOK/2) * 16; // 8 KB
    size_t off_aA = off_sb + (size_t)K_TOK * 4;      // N*16
    size_t off_sa = off_aA + (size_t)N * 16;         // N*4
    size_t off_g  = off_sa + (size_t)N * 4;          // N*32*4
    size_t need_frame = off_sa + (size_t)N * 4;
    size_t need_g     = off_g + (size_t)N * 32 * 4;

    int useFrame = (ws_size >= need_frame) ? 1 : 0;
    int useG     = (ws_size >= need_g) ? 1 : 0;

    float4* bA  = (float4*)((char*)d_ws + off_bA);
    float4* bB  = (float4*)((char*)d_ws + off_bB);
    float*  sb  = (float*)((char*)d_ws + off_sb);
    float4* aA  = (float4*)((char*)d_ws + off_aA);
    float*  saA = (float*)((char*)d_ws + off_sa);
    float*  g   = (float*)((char*)d_ws + off_g);

    hipLaunchKernelGGL(prep_tok, dim3((K_TOK/2 + 255) / 256), dim3(256), 0, stream, mpt, bA, bB, sb);
    if (useFrame)
        hipLaunchKernelGGL(prep_frame, dim3((N + 255) / 256), dim3(256), 0, stream,
                           traj_pos, traj_theta, aA, saA, N);
    if (useG) {
        int total = N * 32;
        hipLaunchKernelGGL(prep_gumbel, dim3((total + 255) / 256), dim3(256), 0, stream,
                           gumbel, g, total);
    }

    int blocks = (N + WPB - 1) / WPB;
    hipLaunchKernelGGL(topk_kernel, dim3(blocks), dim3(BLK), 0, stream,
                       traj_pos, traj_theta, bA, bB, sb, aA, saA, g,
                       token_src, gumbel, out, N, useFrame, useG);
}

// Round 10
// 108.838 us; speedup vs baseline: 3.8961x; 1.1925x over previous
//
#include <hip/hip_runtime.h>
#include <cstdint>
#include <math.h>

#define K_TOK 2048
#define NPAIR 16      // token pairs per lane (K_TOK / 2 / 64)
#define BLK   256
#define WPB   4       // waves (=rows) per block, 1 row per wave

typedef float v2f __attribute__((ext_vector_type(2)));

// monotonic float->uint key (total order == float order, handles negatives)
__device__ __forceinline__ uint32_t f2key(float f) {
    uint32_t u = __float_as_uint(f);
    return u ^ ((uint32_t)(((int32_t)u) >> 31) | 0x80000000u);
}

// ---------------- DPP wave64 primitives (ctrl args constexpr) ----------------
template<int CTRL, int RM, int BM, bool BC>
__device__ __forceinline__ int dpp_i(int old, int v) {
    return __builtin_amdgcn_update_dpp(old, v, CTRL, RM, BM, BC);
}
__device__ __forceinline__ int wave_sum(int v) {
    v += dpp_i<0x111, 0xf, 0xf, true >(0, v);
    v += dpp_i<0x112, 0xf, 0xf, true >(0, v);
    v += dpp_i<0x114, 0xf, 0xf, true >(0, v);
    v += dpp_i<0x118, 0xf, 0xf, true >(0, v);
    v += dpp_i<0x142, 0xa, 0xf, false>(0, v);
    v += dpp_i<0x143, 0xc, 0xf, false>(0, v);
    return __builtin_amdgcn_readlane(v, 63);
}
__device__ __forceinline__ int wave_scan_incl(int v) {
    v += dpp_i<0x111, 0xf, 0xf, true >(0, v);
    v += dpp_i<0x112, 0xf, 0xf, true >(0, v);
    v += dpp_i<0x114, 0xf, 0xf, true >(0, v);
    v += dpp_i<0x118, 0xf, 0xf, true >(0, v);
    v += dpp_i<0x142, 0xa, 0xf, false>(0, v);
    v += dpp_i<0x143, 0xc, 0xf, false>(0, v);
    return v;
}
template<int M>
__device__ __forceinline__ uint32_t lxu(uint32_t x) {
    if constexpr (M == 1)       return (uint32_t)dpp_i<0xB1,  0xf, 0xf, true>(0, (int)x);
    else if constexpr (M == 2)  return (uint32_t)dpp_i<0x4E,  0xf, 0xf, true>(0, (int)x);
    else if constexpr (M == 8)  return (uint32_t)dpp_i<0x128, 0xf, 0xf, true>(0, (int)x);
    else if constexpr (M == 4)  return (uint32_t)__builtin_amdgcn_ds_swizzle((int)x, 0x101F);
    else if constexpr (M == 16) return (uint32_t)__builtin_amdgcn_ds_swizzle((int)x, 0x401F);
    else                        return (uint32_t)__shfl_xor((int)x, 32, 64);
}
template<int M>
__device__ __forceinline__ uint64_t lxu64(uint64_t x) {
    uint32_t h = lxu<M>((uint32_t)(x >> 32));
    uint32_t l = lxu<M>((uint32_t)x);
    return ((uint64_t)h << 32) | l;
}

// ---------------- prep kernels (validated bit-exact R1-R9) ----------------
// Pair-interleaved B: bpair[2P] = {b2[2P],b2[2P+1],b3[2P],b3[2P+1]},
//                     bpair[2P+1] = {b4[2P],b4[2P+1],b5[2P],b5[2P+1]}
__global__ void prep_tok(const float* __restrict__ mpt,
                         float4* __restrict__ bpair, float* __restrict__ sbout) {
    #pragma clang fp contract(off)
    int P = blockIdx.x * blockDim.x + threadIdx.x;
    if (P >= K_TOK / 2) return;
    int k0 = 2 * P, k1 = 2 * P + 1;
    float u0 = mpt[k0*6+0], u1 = mpt[k0*6+1], u2 = mpt[k0*6+2];
    float u3 = mpt[k0*6+3], u4 = mpt[k0*6+4], u5 = mpt[k0*6+5];
    float w0 = mpt[k1*6+0], w1 = mpt[k1*6+1], w2 = mpt[k1*6+2];
    float w3 = mpt[k1*6+3], w4 = mpt[k1*6+4], w5 = mpt[k1*6+5];
    float s0 = ((((u0*u0+u1*u1)+u2*u2)+u3*u3)+u4*u4)+u5*u5;
    float s1 = ((((w0*w0+w1*w1)+w2*w2)+w3*w3)+w4*w4)+w5*w5;
    bpair[2*P]   = make_float4(u2, w2, u3, w3);
    bpair[2*P+1] = make_float4(u4, w4, u5, w5);
    sbout[k0] = s0; sbout[k1] = s1;
}

__global__ void prep_frame(const float* __restrict__ traj_pos,
                           const float* __restrict__ traj_theta,
                           float4* __restrict__ aA, float* __restrict__ saA, int N) {
    #pragma clang fp contract(off)
    int n = blockIdx.x * blockDim.x + threadIdx.x;
    if (n >= N) return;
    const float* tp = traj_pos + (size_t)n*6;
    float p0x=tp[0], p0y=tp[1];
    float dx1=tp[2]-p0x, dy1=tp[3]-p0y;
    float dx2=tp[4]-p0x, dy2=tp[5]-p0y;
    float th = traj_theta[n];
    float c = (float)cos((double)th);
    float s = (float)sin((double)th);
    float ns = -s;
    float a2 = c*dx1 + s*dy1;
    float a3 = ns*dx1 + c*dy1;
    float a4 = c*dx2 + s*dy2;
    float a5 = ns*dx2 + c*dy2;
    float q2=a2*a2,q3=a3*a3,q4=a4*a4,q5=a5*a5;
    float sa = ((q2+q3)+q4)+q5;
    aA[n] = make_float4(a2,a3,a4,a5);
    saA[n] = sa;
}

__global__ void prep_gumbel(const float* __restrict__ gu, float* __restrict__ g, int total) {
    #pragma clang fp contract(off)
    int i = blockIdx.x * blockDim.x + threadIdx.x;
    if (i >= total) return;
    const float C1F = (float)(1.0 - 2.0*1e-7);
    float u = gu[i];
    float t = u * C1F;
    t = t + 1e-7f;
    float li = (float)log((double)t);
    float ni = -li;
    float lo = (float)log((double)ni);
    g[i] = -lo;
}

// candidate mask over pairs + wave count in one pass (R6-validated form)
__device__ __forceinline__ int count_mask(const v2f (&dd2)[NPAIR], float T, uint32_t* cmo) {
    uint32_t cm = 0;
    #pragma unroll
    for (int p = 0; p < NPAIR; ++p) {
        if (dd2[p].x <= T) cm |= (1u << (2*p));
        if (dd2[p].y <= T) cm |= (1u << (2*p+1));
    }
    *cmo = cm;
    return wave_sum(__popc(cm));
}

// ---------------- main kernel (R6 structure, 4-wave blocks) ----------------
__global__ __launch_bounds__(BLK) void topk_kernel(
        const float* __restrict__ traj_pos, const float* __restrict__ traj_theta,
        const float4* __restrict__ bpair, const float* __restrict__ sbg,
        const float4* __restrict__ aAg, const float* __restrict__ saAg,
        const float* __restrict__ gtab,
        const float* __restrict__ token_src, const float* __restrict__ gumbel,
        float* __restrict__ out, int Nrows, int useFrame, int useG) {
    #pragma clang fp contract(off)
    __shared__ float    sSB[K_TOK];            // 8 KB
    __shared__ uint32_t sCidx[WPB][64];        // 1 KB

    const int tid = threadIdx.x;
    {
        const float4* s4 = (const float4*)sbg;
        #pragma unroll
        for (int r = 0; r < 2; ++r)
            ((float4*)sSB)[tid + r * BLK] = s4[tid + r * BLK];   // 8 KB staged
    }
    __syncthreads();

    const int wv   = tid >> 6;
    const int lane = tid & 63;
    const int n    = blockIdx.x * WPB + wv;
    if (n >= Nrows) return;

    // ---- per-row local frame
    float a2, a3, a4, a5, sa;
    if (useFrame) {
        float4 av = aAg[n];
        a2 = av.x; a3 = av.y; a4 = av.z; a5 = av.w;
        sa = saAg[n];
    } else {
        const float* tp = traj_pos + (size_t)n * 6;
        float p0x = tp[0], p0y = tp[1];
        float dx1 = tp[2] - p0x, dy1 = tp[3] - p0y;
        float dx2 = tp[4] - p0x, dy2 = tp[5] - p0y;
        float th = traj_theta[n];
        float c = (float)cos((double)th);
        float s = (float)sin((double)th);
        float ns = -s;
        a2 = c*dx1 + s*dy1;
        a3 = ns*dx1 + c*dy1;
        a4 = c*dx2 + s*dy2;
        a5 = ns*dx2 + c*dy2;
        float q2 = a2*a2, q3 = a3*a3, q4 = a4*a4, q5 = a5*a5;
        sa = ((q2 + q3) + q4) + q5;
    }

    // ---- packed distances (per-component rounding == validated scalar chain)
    const v2f a2v = { a2, a2 }, a3v = { a3, a3 }, a4v = { a4, a4 }, a5v = { a5, a5 };
    const v2f sav = { sa, sa }, n2v = { -2.0f, -2.0f };
    v2f dd2[NPAIR];
    v2f lm2 = { INFINITY, INFINITY };
    #pragma unroll
    for (int p = 0; p < NPAIR; ++p) {
        int P = p * 64 + lane;
        float4 q0 = bpair[2*P];
        float4 q1 = bpair[2*P+1];
        v2f sb2 = ((const v2f*)sSB)[P];
        v2f bx = { q0.x, q0.y }, by = { q0.z, q0.w };
        v2f bz = { q1.x, q1.y }, bw = { q1.z, q1.w };
        v2f d = a2v * bx;                              // pk_mul
        d = __builtin_elementwise_fma(a3v, by, d);     // pk_fma
        d = __builtin_elementwise_fma(a4v, bz, d);
        d = __builtin_elementwise_fma(a5v, bw, d);
        v2f ss = sav + sb2;                            // pk_add
        v2f dist = __builtin_elementwise_fma(n2v, d, ss);  // == (sa+sb) - 2*d0 bitwise
        dd2[p] = dist;
        lm2.x = fminf(lm2.x, dist.x);
        lm2.y = fminf(lm2.y, dist.y);
    }
    float lmin = fminf(lm2.x, lm2.y);

    // ---- bitonic ascending sort of lane minima (T0 = 31st order stat)
    {
        float v = lmin;
        #define FST(K2,J2) { float o = __uint_as_float(lxu<J2>(__float_as_uint(v))); \
            bool up = ((lane & K2) == 0) == ((lane & J2) == 0); \
            v = up ? fminf(v, o) : fmaxf(v, o); }
        FST(2,1)
        FST(4,2)  FST(4,1)
        FST(8,4)  FST(8,2)  FST(8,1)
        FST(16,8) FST(16,4) FST(16,2) FST(16,1)
        FST(32,16) FST(32,8) FST(32,4) FST(32,2) FST(32,1)
        FST(64,32) FST(64,16) FST(64,8) FST(64,4) FST(64,2) FST(64,1)
        #undef FST
        lmin = v;
    }
    float gmn = __uint_as_float((uint32_t)__builtin_amdgcn_readlane((int)__float_as_uint(lmin), 0));
    float T0  = __uint_as_float((uint32_t)__builtin_amdgcn_readlane((int)__float_as_uint(lmin), 31));

    // ---- threshold with count(d <= T) in [32,64]  (R6-validated logic)
    uint32_t cmask = 0;
    int cnt = count_mask(dd2, T0, &cmask);
    bool done = (cnt >= 32 && cnt <= 64);
    float loV = gmn, hiV = T0;
    for (int it = 0; it < 12 && !done; ++it) {
        float mid = 0.5f * (loV + hiV);
        if (!(mid > loV && mid < hiV)) break;
        uint32_t cm2;
        int c = count_mask(dd2, mid, &cm2);
        if (c < 32) loV = mid;
        else if (c > 64) hiV = mid;
        else { cnt = c; cmask = cm2; done = true; }
    }

    if (!done) {
        // exact bitwise binary search fallback (cold, provably correct)
        uint32_t A = 0u; bool found = false; int ccf = 0;
        for (int b = 31; b >= 0; --b) {
            uint32_t T2 = A | ((1u << b) - 1u);
            int cc = 0;
            #pragma unroll
            for (int p = 0; p < NPAIR; ++p) {
                cc += (f2key(dd2[p].x) <= T2) ? 1 : 0;
                cc += (f2key(dd2[p].y) <= T2) ? 1 : 0;
            }
            cc = wave_sum(cc);
            if (cc >= 32) { if (cc <= 64) { A = T2; ccf = cc; found = true; break; } }
            else A |= (1u << b);
        }
        if (!found) {
            int cc = 0;
            #pragma unroll
            for (int p = 0; p < NPAIR; ++p) {
                cc += (f2key(dd2[p].x) <= A) ? 1 : 0;
                cc += (f2key(dd2[p].y) <= A) ? 1 : 0;
            }
            ccf = wave_sum(cc);
        }
        cnt = ccf;
        cmask = 0;
        #pragma unroll
        for (int p = 0; p < NPAIR; ++p) {
            if (f2key(dd2[p].x) <= A) cmask |= (1u << (2*p));
            if (f2key(dd2[p].y) <= A) cmask |= (1u << (2*p+1));
        }
    }
    int cnt_cap = cnt > 64 ? 64 : cnt;

    // ---- sparse compaction: store token INDEX only (E[iters/lane] ~ 0.7)
    {
        int lc  = __popc(cmask);
        int pos = wave_scan_incl(lc) - lc;   // exclusive prefix
        uint32_t m = cmask;
        while (m) {
            int j = __builtin_ctz(m);
            m &= m - 1;
            int token = 2 * ((j >> 1) * 64 + lane) + (j & 1);
            if (pos < 64) sCidx[wv][pos] = (uint32_t)token;
            ++pos;
        }
    }
    asm volatile("s_waitcnt lgkmcnt(0)" ::: "memory");

    // ---- read back + exact recompute (identical op sequence -> identical bits)
    uint64_t bv;
    if (lane < cnt_cap) {
        uint32_t idxv = sCidx[wv][lane];
        uint32_t P = idxv >> 1;
        float4 q0 = bpair[2*P];
        float4 q1 = bpair[2*P+1];
        int h = (int)(idxv & 1u);
        float bx = h ? q0.y : q0.x;
        float by = h ? q0.w : q0.z;
        float bz = h ? q1.y : q1.x;
        float bw = h ? q1.w : q1.z;
        float sbv = sSB[idxv];
        float d0 = a2 * bx;
        d0 = fmaf(a3, by, d0);
        d0 = fmaf(a4, bz, d0);
        d0 = fmaf(a5, bw, d0);
        float ss = sa + sbv;
        float dist = fmaf(-2.0f, d0, ss);
        bv = ((uint64_t)f2key(dist) << 16) | (uint64_t)idxv;
    } else {
        bv = ~0ull;
    }

    // ---- bitonic sort of 64 candidates, ascending (key,idx); slot l -> lane l
    #define UST(K2,J2) { uint64_t o = lxu64<J2>(bv); \
        bool up = ((lane & K2) == 0) == ((lane & J2) == 0); \
        bv = ((o < bv) == up) ? o : bv; }
    UST(2,1)
    UST(4,2)  UST(4,1)
    UST(8,4)  UST(8,2)  UST(8,1)
    UST(16,8) UST(16,4) UST(16,2) UST(16,1)
    UST(32,16) UST(32,8) UST(32,4) UST(32,2) UST(32,1)
    UST(64,32) UST(64,16) UST(64,8) UST(64,4) UST(64,2) UST(64,1)
    #undef UST

    // ---- gumbel-argmax over 32 sorted slots (tie -> lower slot)
    float dsel;
    {
        uint32_t kbits = (uint32_t)(bv >> 16);
        uint32_t mkb = ((uint32_t)((~(int32_t)kbits) >> 31)) | 0x80000000u;
        dsel = __uint_as_float(kbits ^ mkb);
    }
    int tok = (int)(bv & 0xFFFFu);
    uint32_t kh = 0u, kl = 0u;
    if (lane < 32) {
        float neg   = -dsel;
        float logit = (-1e-6f) + neg;
        float g;
        if (useG) {
            g = gtab[(size_t)n * 32 + lane];
        } else {
            const float C1F = (float)(1.0 - 2.0 * 1e-7);
            float u = gumbel[(size_t)n * 32 + lane];
            float t = u * C1F;
            t = t + 1e-7f;
            float li = (float)log((double)t);
            float ni = -li;
            float lo2 = (float)log((double)ni);
            g = -lo2;
        }
        float score = logit + g;
        kh = f2key(score);
        kl = ((uint32_t)(63 - lane) << 11) | (uint32_t)tok;  // tie -> lower slot
    }
    #define MAXST(CTRL, RM) { \
        uint32_t oh = (uint32_t)dpp_i<CTRL, RM, 0xf, false>((int)kh, (int)kh); \
        uint32_t ol = (uint32_t)dpp_i<CTRL, RM, 0xf, false>((int)kl, (int)kl); \
        if (((((uint64_t)oh << 32) | ol)) > ((((uint64_t)kh << 32) | kl))) { kh = oh; kl = ol; } }
    MAXST(0x111, 0xf) MAXST(0x112, 0xf) MAXST(0x114, 0xf) MAXST(0x118, 0xf)
    MAXST(0x142, 0xa) MAXST(0x143, 0xc)
    #undef MAXST
    uint32_t wl = (uint32_t)__builtin_amdgcn_readlane((int)kl, 63);
    int tw = (int)(wl & 0x7FFu);

    if (lane < 22) out[(size_t)n * 22 + lane] = token_src[(size_t)tw * 22 + lane];
}

extern "C" void kernel_launch(void* const* d_in, const int* in_sizes, int n_in,
                              void* d_out, int out_size, void* d_ws, size_t ws_size,
                              hipStream_t stream) {
    const float* traj_pos   = (const float*)d_in[0];
    const float* traj_theta = (const float*)d_in[1];
    const float* mpt        = (const float*)d_in[2];
    const float* token_src  = (const float*)d_in[3];
    const float* gumbel     = (const float*)d_in[4];
    float* out = (float*)d_out;

    int N = in_sizes[0] / 6;

    size_t off_bp = 0;                               // 2048 float4 = 32 KB
    size_t off_sb = off_bp + (size_t)K_TOK * 16;     // 8 KB
    size_t off_aA = off_sb + (size_t)K_TOK * 4;      // N*16
    size_t off_sa = off_aA + (size_t)N * 16;         // N*4
    size_t off_g  = off_sa + (size_t)N * 4;          // N*32*4
    size_t need_frame = off_sa + (size_t)N * 4;
    size_t need_g     = off_g + (size_t)N * 32 * 4;

    int useFrame = (ws_size >= need_frame) ? 1 : 0;
    int useG     = (ws_size >= need_g) ? 1 : 0;

    float4* bp  = (float4*)((char*)d_ws + off_bp);
    float*  sb  = (float*)((char*)d_ws + off_sb);
    float4* aA  = (float4*)((char*)d_ws + off_aA);
    float*  saA = (float*)((char*)d_ws + off_sa);
    float*  g   = (float*)((char*)d_ws + off_g);

    hipLaunchKernelGGL(prep_tok, dim3((K_TOK/2 + 255) / 256), dim3(256), 0, stream, mpt, bp, sb);
    if (useFrame)
        hipLaunchKernelGGL(prep_frame, dim3((N + 255) / 256), dim3(256), 0, stream,
                           traj_pos, traj_theta, aA, saA, N);
    if (useG) {
        int total = N * 32;
        hipLaunchKernelGGL(prep_gumbel, dim3((total + 255) / 256), dim3(256), 0, stream,
                           gumbel, g, total);
    }

    int blocks = (N + WPB - 1) / WPB;
    hipLaunchKernelGGL(topk_kernel, dim3(blocks), dim3(BLK), 0, stream,
                       traj_pos, traj_theta, bp, sb, aA, saA, g,
                       token_src, gumbel, out, N, useFrame, useG);
}

// Round 11
// 101.798 us; speedup vs baseline: 4.1655x; 1.0692x over previous
//
#include <hip/hip_runtime.h>
#include <cstdint>
#include <math.h>

#define K_TOK 2048
#define NPAIR 16      // token pairs per lane (K_TOK / 2 / 64)
#define BLK   256
#define WPB   4       // waves (=rows) per block, 1 row per wave

typedef float v2f __attribute__((ext_vector_type(2)));

// monotonic float->uint key (total order == float order, handles negatives)
__device__ __forceinline__ uint32_t f2key(float f) {
    uint32_t u = __float_as_uint(f);
    return u ^ ((uint32_t)(((int32_t)u) >> 31) | 0x80000000u);
}

// ---------------- DPP wave64 primitives (ctrl args constexpr) ----------------
template<int CTRL, int RM, int BM, bool BC>
__device__ __forceinline__ int dpp_i(int old, int v) {
    return __builtin_amdgcn_update_dpp(old, v, CTRL, RM, BM, BC);
}
__device__ __forceinline__ int wave_sum(int v) {
    v += dpp_i<0x111, 0xf, 0xf, true >(0, v);
    v += dpp_i<0x112, 0xf, 0xf, true >(0, v);
    v += dpp_i<0x114, 0xf, 0xf, true >(0, v);
    v += dpp_i<0x118, 0xf, 0xf, true >(0, v);
    v += dpp_i<0x142, 0xa, 0xf, false>(0, v);
    v += dpp_i<0x143, 0xc, 0xf, false>(0, v);
    return __builtin_amdgcn_readlane(v, 63);
}
__device__ __forceinline__ int wave_scan_incl(int v) {
    v += dpp_i<0x111, 0xf, 0xf, true >(0, v);
    v += dpp_i<0x112, 0xf, 0xf, true >(0, v);
    v += dpp_i<0x114, 0xf, 0xf, true >(0, v);
    v += dpp_i<0x118, 0xf, 0xf, true >(0, v);
    v += dpp_i<0x142, 0xa, 0xf, false>(0, v);
    v += dpp_i<0x143, 0xc, 0xf, false>(0, v);
    return v;
}
template<int M>
__device__ __forceinline__ uint32_t lxu(uint32_t x) {
    if constexpr (M == 1)       return (uint32_t)dpp_i<0xB1,  0xf, 0xf, true>(0, (int)x);
    else if constexpr (M == 2)  return (uint32_t)dpp_i<0x4E,  0xf, 0xf, true>(0, (int)x);
    else if constexpr (M == 8)  return (uint32_t)dpp_i<0x128, 0xf, 0xf, true>(0, (int)x);
    else if constexpr (M == 4)  return (uint32_t)__builtin_amdgcn_ds_swizzle((int)x, 0x101F);
    else if constexpr (M == 16) return (uint32_t)__builtin_amdgcn_ds_swizzle((int)x, 0x401F);
    else                        return (uint32_t)__shfl_xor((int)x, 32, 64);
}
template<int M>
__device__ __forceinline__ uint64_t lxu64(uint64_t x) {
    uint32_t h = lxu<M>((uint32_t)(x >> 32));
    uint32_t l = lxu<M>((uint32_t)x);
    return ((uint64_t)h << 32) | l;
}

// ---------------- merged prep kernel (all op sequences bit-identical R1-R10) ----
// thread i < N*32  : gumbel table g[i]
// thread i < N     : frame aA[i], saA[i]
// thread i < K_TOK/2: token pair streams
__global__ void prep_all(const float* __restrict__ mpt,
                         float4* __restrict__ bpair, float* __restrict__ sbout,
                         const float* __restrict__ traj_pos,
                         const float* __restrict__ traj_theta,
                         float4* __restrict__ aA, float* __restrict__ saA,
                         const float* __restrict__ gu, float* __restrict__ g,
                         int N, int useFrame, int useG) {
    #pragma clang fp contract(off)
    int i = blockIdx.x * blockDim.x + threadIdx.x;

    if (useG && i < N * 32) {
        const float C1F = (float)(1.0 - 2.0*1e-7);
        float u = gu[i];
        float t = u * C1F;
        t = t + 1e-7f;
        float li = (float)log((double)t);
        float ni = -li;
        float lo = (float)log((double)ni);
        g[i] = -lo;
    }

    if (useFrame && i < N) {
        const float* tp = traj_pos + (size_t)i*6;
        float p0x=tp[0], p0y=tp[1];
        float dx1=tp[2]-p0x, dy1=tp[3]-p0y;
        float dx2=tp[4]-p0x, dy2=tp[5]-p0y;
        float th = traj_theta[i];
        float c = (float)cos((double)th);
        float s = (float)sin((double)th);
        float ns = -s;
        float a2 = c*dx1 + s*dy1;
        float a3 = ns*dx1 + c*dy1;
        float a4 = c*dx2 + s*dy2;
        float a5 = ns*dx2 + c*dy2;
        float q2=a2*a2,q3=a3*a3,q4=a4*a4,q5=a5*a5;
        float sa = ((q2+q3)+q4)+q5;
        aA[i] = make_float4(a2,a3,a4,a5);
        saA[i] = sa;
    }

    if (i < K_TOK / 2) {
        int k0 = 2 * i, k1 = 2 * i + 1;
        float u0 = mpt[k0*6+0], u1 = mpt[k0*6+1], u2 = mpt[k0*6+2];
        float u3 = mpt[k0*6+3], u4 = mpt[k0*6+4], u5 = mpt[k0*6+5];
        float w0 = mpt[k1*6+0], w1 = mpt[k1*6+1], w2 = mpt[k1*6+2];
        float w3 = mpt[k1*6+3], w4 = mpt[k1*6+4], w5 = mpt[k1*6+5];
        float s0 = ((((u0*u0+u1*u1)+u2*u2)+u3*u3)+u4*u4)+u5*u5;
        float s1 = ((((w0*w0+w1*w1)+w2*w2)+w3*w3)+w4*w4)+w5*w5;
        bpair[2*i]   = make_float4(u2, w2, u3, w3);
        bpair[2*i+1] = make_float4(u4, w4, u5, w5);
        sbout[k0] = s0; sbout[k1] = s1;
    }
}

// candidate mask over pairs + wave count in one pass (R6/R10-validated form)
__device__ __forceinline__ int count_mask(const v2f (&dd2)[NPAIR], float T, uint32_t* cmo) {
    uint32_t cm = 0;
    #pragma unroll
    for (int p = 0; p < NPAIR; ++p) {
        if (dd2[p].x <= T) cm |= (1u << (2*p));
        if (dd2[p].y <= T) cm |= (1u << (2*p+1));
    }
    *cmo = cm;
    return wave_sum(__popc(cm));
}

// ---------------- main kernel (byte-identical to R10) ----------------
__global__ __launch_bounds__(BLK) void topk_kernel(
        const float* __restrict__ traj_pos, const float* __restrict__ traj_theta,
        const float4* __restrict__ bpair, const float* __restrict__ sbg,
        const float4* __restrict__ aAg, const float* __restrict__ saAg,
        const float* __restrict__ gtab,
        const float* __restrict__ token_src, const float* __restrict__ gumbel,
        float* __restrict__ out, int Nrows, int useFrame, int useG) {
    #pragma clang fp contract(off)
    __shared__ float    sSB[K_TOK];            // 8 KB
    __shared__ uint32_t sCidx[WPB][64];        // 1 KB

    const int tid = threadIdx.x;
    {
        const float4* s4 = (const float4*)sbg;
        #pragma unroll
        for (int r = 0; r < 2; ++r)
            ((float4*)sSB)[tid + r * BLK] = s4[tid + r * BLK];   // 8 KB staged
    }
    __syncthreads();

    const int wv   = tid >> 6;
    const int lane = tid & 63;
    const int n    = blockIdx.x * WPB + wv;
    if (n >= Nrows) return;

    // ---- per-row local frame
    float a2, a3, a4, a5, sa;
    if (useFrame) {
        float4 av = aAg[n];
        a2 = av.x; a3 = av.y; a4 = av.z; a5 = av.w;
        sa = saAg[n];
    } else {
        const float* tp = traj_pos + (size_t)n * 6;
        float p0x = tp[0], p0y = tp[1];
        float dx1 = tp[2] - p0x, dy1 = tp[3] - p0y;
        float dx2 = tp[4] - p0x, dy2 = tp[5] - p0y;
        float th = traj_theta[n];
        float c = (float)cos((double)th);
        float s = (float)sin((double)th);
        float ns = -s;
        a2 = c*dx1 + s*dy1;
        a3 = ns*dx1 + c*dy1;
        a4 = c*dx2 + s*dy2;
        a5 = ns*dx2 + c*dy2;
        float q2 = a2*a2, q3 = a3*a3, q4 = a4*a4, q5 = a5*a5;
        sa = ((q2 + q3) + q4) + q5;
    }

    // ---- packed distances (per-component rounding == validated scalar chain)
    const v2f a2v = { a2, a2 }, a3v = { a3, a3 }, a4v = { a4, a4 }, a5v = { a5, a5 };
    const v2f sav = { sa, sa }, n2v = { -2.0f, -2.0f };
    v2f dd2[NPAIR];
    v2f lm2 = { INFINITY, INFINITY };
    #pragma unroll
    for (int p = 0; p < NPAIR; ++p) {
        int P = p * 64 + lane;
        float4 q0 = bpair[2*P];
        float4 q1 = bpair[2*P+1];
        v2f sb2 = ((const v2f*)sSB)[P];
        v2f bx = { q0.x, q0.y }, by = { q0.z, q0.w };
        v2f bz = { q1.x, q1.y }, bw = { q1.z, q1.w };
        v2f d = a2v * bx;                              // pk_mul
        d = __builtin_elementwise_fma(a3v, by, d);     // pk_fma
        d = __builtin_elementwise_fma(a4v, bz, d);
        d = __builtin_elementwise_fma(a5v, bw, d);
        v2f ss = sav + sb2;                            // pk_add
        v2f dist = __builtin_elementwise_fma(n2v, d, ss);  // == (sa+sb) - 2*d0 bitwise
        dd2[p] = dist;
        lm2.x = fminf(lm2.x, dist.x);
        lm2.y = fminf(lm2.y, dist.y);
    }
    float lmin = fminf(lm2.x, lm2.y);

    // ---- bitonic ascending sort of lane minima (T0 = 31st order stat)
    {
        float v = lmin;
        #define FST(K2,J2) { float o = __uint_as_float(lxu<J2>(__float_as_uint(v))); \
            bool up = ((lane & K2) == 0) == ((lane & J2) == 0); \
            v = up ? fminf(v, o) : fmaxf(v, o); }
        FST(2,1)
        FST(4,2)  FST(4,1)
        FST(8,4)  FST(8,2)  FST(8,1)
        FST(16,8) FST(16,4) FST(16,2) FST(16,1)
        FST(32,16) FST(32,8) FST(32,4) FST(32,2) FST(32,1)
        FST(64,32) FST(64,16) FST(64,8) FST(64,4) FST(64,2) FST(64,1)
        #undef FST
        lmin = v;
    }
    float gmn = __uint_as_float((uint32_t)__builtin_amdgcn_readlane((int)__float_as_uint(lmin), 0));
    float T0  = __uint_as_float((uint32_t)__builtin_amdgcn_readlane((int)__float_as_uint(lmin), 31));

    // ---- threshold with count(d <= T) in [32,64]  (R6-validated logic)
    uint32_t cmask = 0;
    int cnt = count_mask(dd2, T0, &cmask);
    bool done = (cnt >= 32 && cnt <= 64);
    float loV = gmn, hiV = T0;
    for (int it = 0; it < 12 && !done; ++it) {
        float mid = 0.5f * (loV + hiV);
        if (!(mid > loV && mid < hiV)) break;
        uint32_t cm2;
        int c = count_mask(dd2, mid, &cm2);
        if (c < 32) loV = mid;
        else if (c > 64) hiV = mid;
        else { cnt = c; cmask = cm2; done = true; }
    }

    if (!done) {
        // exact bitwise binary search fallback (cold, provably correct)
        uint32_t A = 0u; bool found = false; int ccf = 0;
        for (int b = 31; b >= 0; --b) {
            uint32_t T2 = A | ((1u << b) - 1u);
            int cc = 0;
            #pragma unroll
            for (int p = 0; p < NPAIR; ++p) {
                cc += (f2key(dd2[p].x) <= T2) ? 1 : 0;
                cc += (f2key(dd2[p].y) <= T2) ? 1 : 0;
            }
            cc = wave_sum(cc);
            if (cc >= 32) { if (cc <= 64) { A = T2; ccf = cc; found = true; break; } }
            else A |= (1u << b);
        }
        if (!found) {
            int cc = 0;
            #pragma unroll
            for (int p = 0; p < NPAIR; ++p) {
                cc += (f2key(dd2[p].x) <= A) ? 1 : 0;
                cc += (f2key(dd2[p].y) <= A) ? 1 : 0;
            }
            ccf = wave_sum(cc);
        }
        cnt = ccf;
        cmask = 0;
        #pragma unroll
        for (int p = 0; p < NPAIR; ++p) {
            if (f2key(dd2[p].x) <= A) cmask |= (1u << (2*p));
            if (f2key(dd2[p].y) <= A) cmask |= (1u << (2*p+1));
        }
    }
    int cnt_cap = cnt > 64 ? 64 : cnt;

    // ---- sparse compaction: store token INDEX only (E[iters/lane] ~ 0.7)
    {
        int lc  = __popc(cmask);
        int pos = wave_scan_incl(lc) - lc;   // exclusive prefix
        uint32_t m = cmask;
        while (m) {
            int j = __builtin_ctz(m);
            m &= m - 1;
            int token = 2 * ((j >> 1) * 64 + lane) + (j & 1);
            if (pos < 64) sCidx[wv][pos] = (uint32_t)token;
            ++pos;
        }
    }
    asm volatile("s_waitcnt lgkmcnt(0)" ::: "memory");

    // ---- read back + exact recompute (identical op sequence -> identical bits)
    uint64_t bv;
    if (lane < cnt_cap) {
        uint32_t idxv = sCidx[wv][lane];
        uint32_t P = idxv >> 1;
        float4 q0 = bpair[2*P];
        float4 q1 = bpair[2*P+1];
        int h = (int)(idxv & 1u);
        float bx = h ? q0.y : q0.x;
        float by = h ? q0.w : q0.z;
        float bz = h ? q1.y : q1.x;
        float bw = h ? q1.w : q1.z;
        float sbv = sSB[idxv];
        float d0 = a2 * bx;
        d0 = fmaf(a3, by, d0);
        d0 = fmaf(a4, bz, d0);
        d0 = fmaf(a5, bw, d0);
        float ss = sa + sbv;
        float dist = fmaf(-2.0f, d0, ss);
        bv = ((uint64_t)f2key(dist) << 16) | (uint64_t)idxv;
    } else {
        bv = ~0ull;
    }

    // ---- bitonic sort of 64 candidates, ascending (key,idx); slot l -> lane l
    #define UST(K2,J2) { uint64_t o = lxu64<J2>(bv); \
        bool up = ((lane & K2) == 0) == ((lane & J2) == 0); \
        bv = ((o < bv) == up) ? o : bv; }
    UST(2,1)
    UST(4,2)  UST(4,1)
    UST(8,4)  UST(8,2)  UST(8,1)
    UST(16,8) UST(16,4) UST(16,2) UST(16,1)
    UST(32,16) UST(32,8) UST(32,4) UST(32,2) UST(32,1)
    UST(64,32) UST(64,16) UST(64,8) UST(64,4) UST(64,2) UST(64,1)
    #undef UST

    // ---- gumbel-argmax over 32 sorted slots (tie -> lower slot)
    float dsel;
    {
        uint32_t kbits = (uint32_t)(bv >> 16);
        uint32_t mkb = ((uint32_t)((~(int32_t)kbits) >> 31)) | 0x80000000u;
        dsel = __uint_as_float(kbits ^ mkb);
    }
    int tok = (int)(bv & 0xFFFFu);
    uint32_t kh = 0u, kl = 0u;
    if (lane < 32) {
        float neg   = -dsel;
        float logit = (-1e-6f) + neg;
        float g;
        if (useG) {
            g = gtab[(size_t)n * 32 + lane];
        } else {
            const float C1F = (float)(1.0 - 2.0 * 1e-7);
            float u = gumbel[(size_t)n * 32 + lane];
            float t = u * C1F;
            t = t + 1e-7f;
            float li = (float)log((double)t);
            float ni = -li;
            float lo2 = (float)log((double)ni);
            g = -lo2;
        }
        float score = logit + g;
        kh = f2key(score);
        kl = ((uint32_t)(63 - lane) << 11) | (uint32_t)tok;  // tie -> lower slot
    }
    #define MAXST(CTRL, RM) { \
        uint32_t oh = (uint32_t)dpp_i<CTRL, RM, 0xf, false>((int)kh, (int)kh); \
        uint32_t ol = (uint32_t)dpp_i<CTRL, RM, 0xf, false>((int)kl, (int)kl); \
        if (((((uint64_t)oh << 32) | ol)) > ((((uint64_t)kh << 32) | kl))) { kh = oh; kl = ol; } }
    MAXST(0x111, 0xf) MAXST(0x112, 0xf) MAXST(0x114, 0xf) MAXST(0x118, 0xf)
    MAXST(0x142, 0xa) MAXST(0x143, 0xc)
    #undef MAXST
    uint32_t wl = (uint32_t)__builtin_amdgcn_readlane((int)kl, 63);
    int tw = (int)(wl & 0x7FFu);

    if (lane < 22) out[(size_t)n * 22 + lane] = token_src[(size_t)tw * 22 + lane];
}

extern "C" void kernel_launch(void* const* d_in, const int* in_sizes, int n_in,
                              void* d_out, int out_size, void* d_ws, size_t ws_size,
                              hipStream_t stream) {
    const float* traj_pos   = (const float*)d_in[0];
    const float* traj_theta = (const float*)d_in[1];
    const float* mpt        = (const float*)d_in[2];
    const float* token_src  = (const float*)d_in[3];
    const float* gumbel     = (const float*)d_in[4];
    float* out = (float*)d_out;

    int N = in_sizes[0] / 6;

    size_t off_bp = 0;                               // 2048 float4 = 32 KB
    size_t off_sb = off_bp + (size_t)K_TOK * 16;     // 8 KB
    size_t off_aA = off_sb + (size_t)K_TOK * 4;      // N*16
    size_t off_sa = off_aA + (size_t)N * 16;         // N*4
    size_t off_g  = off_sa + (size_t)N * 4;          // N*32*4
    size_t need_frame = off_sa + (size_t)N * 4;
    size_t need_g     = off_g + (size_t)N * 32 * 4;

    int useFrame = (ws_size >= need_frame) ? 1 : 0;
    int useG     = (ws_size >= need_g) ? 1 : 0;

    float4* bp  = (float4*)((char*)d_ws + off_bp);
    float*  sb  = (float*)((char*)d_ws + off_sb);
    float4* aA  = (float4*)((char*)d_ws + off_aA);
    float*  saA = (float*)((char*)d_ws + off_sa);
    float*  g   = (float*)((char*)d_ws + off_g);

    // single merged prep launch: gumbel (N*32) + frame (N) + token pairs (K/2)
    int prep_total = useG ? (N * 32) : (useFrame ? (N > K_TOK/2 ? N : K_TOK/2) : K_TOK/2);
    hipLaunchKernelGGL(prep_all, dim3((prep_total + 255) / 256), dim3(256), 0, stream,
                       mpt, bp, sb, traj_pos, traj_theta, aA, saA, gumbel, g,
                       N, useFrame, useG);

    int blocks = (N + WPB - 1) / WPB;
    hipLaunchKernelGGL(topk_kernel, dim3(blocks), dim3(BLK), 0, stream,
                       traj_pos, traj_theta, bp, sb, aA, saA, g,
                       token_src, gumbel, out, N, useFrame, useG);
}